// Round 5
// baseline (1634.307 us; speedup 1.0000x reference)
//
#include <hip/hip_runtime.h>
#include <math.h>

typedef unsigned short u16;
typedef __bf16 bf16x8 __attribute__((ext_vector_type(8)));
typedef short s16x8 __attribute__((ext_vector_type(8)));
typedef short s16x4 __attribute__((ext_vector_type(4)));
typedef float f32x4 __attribute__((ext_vector_type(4)));

__device__ __forceinline__ u16 f2bf(float f) {
  union { float f; unsigned u; } v; v.f = f;
  unsigned u = v.u;
  unsigned r = u + 0x7fffu + ((u >> 16) & 1u);
  return (u16)(r >> 16);
}
__device__ __forceinline__ float bf2f(u16 h) {
  union { unsigned u; float f; } v; v.u = ((unsigned)h) << 16;
  return v.f;
}
__device__ __forceinline__ float fast_softplus(float x) {
  return (x > 20.f) ? x : __logf(1.f + __expf(x));
}
__device__ __forceinline__ float fast_sig(float x) {
  return __builtin_amdgcn_rcpf(1.f + __expf(-x));
}
// HW packed f32->bf16 (RNE; same rounding as f2bf). No builtin on gfx950.
__device__ __forceinline__ unsigned cvtpk_bf16(float lo, float hi) {
  unsigned r;
  asm volatile("v_cvt_pk_bf16_f32 %0, %1, %2" : "=v"(r) : "v"(lo), "v"(hi));
  return r;
}

__device__ __forceinline__ void gld_lds16(const u16* g, u16* l) {
  __builtin_amdgcn_global_load_lds(
      (const __attribute__((address_space(1))) unsigned int*)g,
      (__attribute__((address_space(3))) unsigned int*)l, 16, 0, 0);
}

// ---------------------------------------------------------------------------
// fp32 -> bf16 weight conversion, zero-pads [n_valid, n)  (small weights only)
__global__ __launch_bounds__(256)
void f32_to_bf16_k(const float* __restrict__ src, u16* __restrict__ dst,
                   int n, int n_valid) {
  int i = (blockIdx.x * 256 + threadIdx.x) * 4;
  if (i >= n) return;
  s16x4 o;
  if (i + 3 < n_valid) {
    float4 v = *(const float4*)(src + i);
    o[0] = (short)f2bf(v.x); o[1] = (short)f2bf(v.y);
    o[2] = (short)f2bf(v.z); o[3] = (short)f2bf(v.w);
  } else {
    o[0] = 0; o[1] = 0; o[2] = 0; o[3] = 0;
  }
  *(s16x4*)(dst + i) = o;
}

// ---------------------------------------------------------------------------
// GEMM v2.2 (small-N shapes): C[M,N] = A[M,K](bf16) @ B[N,K](bf16)^T
// BM=64, BK=64, BN template {64,128}. Double-buffered LDS, one-tile-ahead
// prefetch with COUNTED vmcnt. XOR-swizzled LDS on DMA source + fragment read.
// SPLITK>1: blockIdx.z computes K-slice, writes partial at z*M*Nc (MODE 0 only).
template <int BN, int MODE, int SPLITK>
__global__ __launch_bounds__(256)
void gemm2(const u16* __restrict__ A, const u16* __restrict__ B,
           float* __restrict__ C, u16* __restrict__ Cb,
           const u16* __restrict__ aux, int M, int Nc, int K) {
  constexpr int NJ = BN / 32;
  constexpr int BISS = BN / 32;
  constexpr int ABUF = 64 * 64;
  constexpr int BBUF = BN * 64;
  __shared__ __align__(16) u16 As[2 * ABUF];
  __shared__ __align__(16) u16 Bs[2 * BBUF];
  const int tid = threadIdx.x;
  const int tm0 = blockIdx.y * 64;
  const int tn0 = blockIdx.x * BN;
  const int kslice = K / SPLITK;
  const int k0 = blockIdx.z * kslice;
  const int wave = tid >> 6;
  const int lane = tid & 63;
  const int wm = (wave >> 1) * 32;
  const int wn = (wave & 1) * (BN / 2);
  const int frow = lane & 15;
  const int fc = lane >> 4;
  const int rmask = frow & 7;

  const int r0 = tid >> 3;
  const int csw = (((tid & 7) ^ (r0 & 7)) << 3);
  const u16* gA = A + (size_t)(tm0 + r0) * K + k0 + csw;
  const u16* gB = B + (size_t)(tn0 + r0) * K + k0 + csw;
  u16* lA = &As[tid * 8];
  u16* lB = &Bs[tid * 8];

  f32x4 acc[2][NJ];
  f32x4 zero = {0.f, 0.f, 0.f, 0.f};
#pragma unroll
  for (int i = 0; i < 2; ++i)
#pragma unroll
    for (int j = 0; j < NJ; ++j) acc[i][j] = zero;

  auto stage = [&](int bi) {
    gld_lds16(gA, lA + bi * ABUF);
    gld_lds16(gA + (size_t)32 * K, lA + bi * ABUF + 2048);
#pragma unroll
    for (int b = 0; b < BISS; ++b)
      gld_lds16(gB + (size_t)32 * b * K, lB + bi * BBUF + b * 2048);
    gA += 64; gB += 64;
  };

  stage(0);
  const int nt = kslice >> 6;
  int buf = 0;
  for (int kt = 0; kt < nt; ++kt) {
    const int nb = buf ^ 1;
    if (kt + 1 < nt) {
      stage(nb);
      if constexpr (BN == 64) asm volatile("s_waitcnt vmcnt(4)" ::: "memory");
      else                    asm volatile("s_waitcnt vmcnt(6)" ::: "memory");
    } else {
      asm volatile("s_waitcnt vmcnt(0)" ::: "memory");
    }
    __builtin_amdgcn_s_barrier();
    __builtin_amdgcn_sched_barrier(0);
    const int ao = buf * ABUF, bo = buf * BBUF;
#pragma unroll
    for (int s = 0; s < 2; ++s) {
      bf16x8 af[2], bfr[NJ];
#pragma unroll
      for (int i = 0; i < 2; ++i) {
        int addr = ao + (wm + i * 16 + frow) * 64 + (((s * 4 + fc) ^ rmask) << 3);
        af[i] = __builtin_bit_cast(bf16x8, *(const s16x8*)&As[addr]);
      }
#pragma unroll
      for (int j = 0; j < NJ; ++j) {
        int addr = bo + (wn + j * 16 + frow) * 64 + (((s * 4 + fc) ^ rmask) << 3);
        bfr[j] = __builtin_bit_cast(bf16x8, *(const s16x8*)&Bs[addr]);
      }
#pragma unroll
      for (int i = 0; i < 2; ++i)
#pragma unroll
        for (int j = 0; j < NJ; ++j)
          acc[i][j] = __builtin_amdgcn_mfma_f32_16x16x32_bf16(af[i], bfr[j], acc[i][j], 0, 0, 0);
    }
    __builtin_amdgcn_s_barrier();
    buf = nb;
  }
  const int ccol = lane & 15;
  const int crow = (lane >> 4) * 4;
  float* Cp = C + (size_t)blockIdx.z * ((size_t)M * Nc);
#pragma unroll
  for (int i = 0; i < 2; ++i) {
#pragma unroll
    for (int j = 0; j < NJ; ++j) {
      int gn = tn0 + wn + j * 16 + ccol;
      if (gn < Nc) {
        size_t base = (size_t)(tm0 + wm + i * 16 + crow) * Nc + gn;
#pragma unroll
        for (int r = 0; r < 4; ++r) {
          float c = acc[i][j][r];
          size_t idx = base + (size_t)r * Nc;
          if (MODE == 0) {
            Cp[idx] = c;
          } else if (MODE == 1) {
            Cb[idx] = f2bf(c * fast_sig(c));
          } else {
            Cb[idx] = f2bf(c * bf2f(aux[idx]));
          }
        }
      }
    }
  }
}

// ---------------------------------------------------------------------------
// GEMM v4.1: BM=128, BN=128, BK=64, 4 waves x 64x64 (4x4 frags), fused
// fp32->bf16 B conversion with TWO-DEEP B register pipeline.
// Per K-step t: issue B-loads(t+2) + A-DMA(t+1); vmcnt(12) retires A(t) AND
// B(t+1) (both >= 1 full iteration old); barrier; MFMA(t); cvt+ds_write of
// B(t+1) (loads already retired -> zero stall); lgkmcnt(0); barrier.
// vmcnt never drains to 0 in the main loop (tail: vmcnt(4)/(0)).
// SPLITK>1: blockIdx.z computes K-slice, writes partial C at z*M*Nc (MODE 0).
template <int MODE, int SPLITK>
__global__ __launch_bounds__(256)
void gemm128f(const u16* __restrict__ A, const float* __restrict__ Bw,
              float* __restrict__ C, u16* __restrict__ Cb,
              const u16* __restrict__ aux, int M, int Nc, int K) {
  __shared__ __align__(16) u16 As[2 * 8192];   // 32 KB
  __shared__ __align__(16) u16 Bs[2 * 8192];   // 32 KB
  const int tid = threadIdx.x;
  const int tm0 = blockIdx.y * 128;
  const int tn0 = blockIdx.x * 128;
  const int kslice = K / SPLITK;
  const int k0 = blockIdx.z * kslice;
  const int wave = tid >> 6;
  const int lane = tid & 63;
  const int wm = (wave >> 1) * 64;
  const int wn = (wave & 1) * 64;
  const int frow = lane & 15;
  const int fc = lane >> 4;
  const int rmask = frow & 7;

  const int r0 = tid >> 3;                        // LDS row (of 32-row group)
  const int csw = (((tid & 7) ^ (r0 & 7)) << 3);  // swizzled chunk offset
  // A: DMA with source-side swizzle, linear LDS dest
  const u16* gA = A + (size_t)(tm0 + r0) * K + k0 + csw;
  u16* lA = &As[tid * 8];
  // B: linear fp32 global source; swizzle applied on the ds_write address
  const float* gBf = Bw + (size_t)(tn0 + r0) * K + k0 + (tid & 7) * 8;
  u16* lBw = &Bs[r0 * 64 + csw];

  f32x4 acc[4][4];
  f32x4 zero = {0.f, 0.f, 0.f, 0.f};
#pragma unroll
  for (int i = 0; i < 4; ++i)
#pragma unroll
    for (int j = 0; j < 4; ++j) acc[i][j] = zero;

  float4 brg[2][4][2];   // two in-flight B tiles (reg sets alternate)
  auto loadB = [&](int s) {
#pragma unroll
    for (int b = 0; b < 4; ++b) {
      const float* p = gBf + (size_t)(32 * b) * K;
      brg[s][b][0] = *(const float4*)p;
      brg[s][b][1] = *(const float4*)(p + 4);
    }
    gBf += 64;
  };
  auto stageA = [&](int bi) {
#pragma unroll
    for (int b = 0; b < 4; ++b)
      gld_lds16(gA + (size_t)(32 * b) * K, lA + bi * 8192 + b * 2048);
    gA += 64;
  };
  auto writeB = [&](int s, int bi) {
#pragma unroll
    for (int b = 0; b < 4; ++b) {
      uint4 o;
      o.x = cvtpk_bf16(brg[s][b][0].x, brg[s][b][0].y);
      o.y = cvtpk_bf16(brg[s][b][0].z, brg[s][b][0].w);
      o.z = cvtpk_bf16(brg[s][b][1].x, brg[s][b][1].y);
      o.w = cvtpk_bf16(brg[s][b][1].z, brg[s][b][1].w);
      *(uint4*)(lBw + bi * 8192 + b * 2048) = o;
    }
  };

  const int nt = kslice >> 6;   // always >= 2 for all shapes used here
  // prologue: B(0)->set0, A(0)->buf0, B(1)->set1; write B(0); drain A(0).
  loadB(0);
  stageA(0);
  if (nt > 1) loadB(1);
  writeB(0, 0);                 // compiler-inserted wait retires B(0) loads
  if (nt > 1) asm volatile("s_waitcnt vmcnt(8) lgkmcnt(0)" ::: "memory");
  else        asm volatile("s_waitcnt vmcnt(0) lgkmcnt(0)" ::: "memory");
  __builtin_amdgcn_s_barrier();
  __builtin_amdgcn_sched_barrier(0);

  int buf = 0;
  for (int kt = 0; kt < nt; ++kt) {
    const int nb = buf ^ 1;
    if (kt + 2 < nt) loadB(kt & 1);       // B(kt+2) into the set freed last iter
    if (kt + 1 < nt) stageA(nb);          // A(kt+1) DMA
    // retire A(kt) (and implicitly B(kt+1), which is older):
    if (kt + 2 < nt)      asm volatile("s_waitcnt vmcnt(12)" ::: "memory");
    else if (kt + 1 < nt) asm volatile("s_waitcnt vmcnt(4)"  ::: "memory");
    else if (kt > 0)      asm volatile("s_waitcnt vmcnt(0)"  ::: "memory");
    if (kt > 0) {
      __builtin_amdgcn_s_barrier();       // B1: A(kt)+B(kt) ready in LDS
      __builtin_amdgcn_sched_barrier(0);
    }
    const int boff = buf * 8192;
#pragma unroll
    for (int s = 0; s < 2; ++s) {
      bf16x8 af[4], bfr[4];
#pragma unroll
      for (int i = 0; i < 4; ++i) {
        int addr = boff + (wm + i * 16 + frow) * 64 + (((s * 4 + fc) ^ rmask) << 3);
        af[i] = __builtin_bit_cast(bf16x8, *(const s16x8*)&As[addr]);
      }
#pragma unroll
      for (int j = 0; j < 4; ++j) {
        int addr = boff + (wn + j * 16 + frow) * 64 + (((s * 4 + fc) ^ rmask) << 3);
        bfr[j] = __builtin_bit_cast(bf16x8, *(const s16x8*)&Bs[addr]);
      }
#pragma unroll
      for (int i = 0; i < 4; ++i)
#pragma unroll
        for (int j = 0; j < 4; ++j)
          acc[i][j] = __builtin_amdgcn_mfma_f32_16x16x32_bf16(af[i], bfr[j], acc[i][j], 0, 0, 0);
    }
    if (kt + 1 < nt) {
      // B(kt+1) loads already retired by the vmcnt above -> stall-free cvt.
      writeB((kt + 1) & 1, nb);
      asm volatile("s_waitcnt lgkmcnt(0)" ::: "memory");
      __builtin_amdgcn_sched_barrier(0);
    }
    __builtin_amdgcn_s_barrier();          // B2: releases buf for reuse
    buf = nb;
  }

  const int ccol = lane & 15;
  const int crow = (lane >> 4) * 4;
  float* Cp = C + (size_t)blockIdx.z * ((size_t)M * Nc);
#pragma unroll
  for (int i = 0; i < 4; ++i) {
#pragma unroll
    for (int j = 0; j < 4; ++j) {
      int gn = tn0 + wn + j * 16 + ccol;
      size_t base = (size_t)(tm0 + wm + i * 16 + crow) * Nc + gn;
#pragma unroll
      for (int r = 0; r < 4; ++r) {
        float c = acc[i][j][r];
        size_t idx = base + (size_t)r * Nc;
        if (MODE == 0) {
          Cp[idx] = c;
        } else if (MODE == 1) {
          Cb[idx] = f2bf(c * fast_sig(c));
        } else {
          Cb[idx] = f2bf(c * bf2f(aux[idx]));
        }
      }
    }
  }
}

// ---------------------------------------------------------------------------
__device__ inline float block_reduce_sum_256(float v) {
  __shared__ float red[4];
  int lane = threadIdx.x & 63, wave = threadIdx.x >> 6;
#pragma unroll
  for (int m = 32; m > 0; m >>= 1) v += __shfl_xor(v, m, 64);
  if (lane == 0) red[wave] = v;
  __syncthreads();
  return red[0] + red[1] + red[2] + red[3];
}

// rmsnorm over C=2048 -> bf16 out
__global__ __launch_bounds__(256)
void rmsnorm2048_k(const float* __restrict__ x, const float* __restrict__ w,
                   u16* __restrict__ y) {
  const int C = 2048;
  const int row = blockIdx.x;
  const int t = threadIdx.x;
  const float4* xr = (const float4*)(x + (size_t)row * C);
  float4 v0 = xr[t];
  float4 v1 = xr[t + 256];
  float ss = v0.x * v0.x + v0.y * v0.y + v0.z * v0.z + v0.w * v0.w +
             v1.x * v1.x + v1.y * v1.y + v1.z * v1.z + v1.w * v1.w;
  float tot = block_reduce_sum_256(ss);
  float sc = rsqrtf(tot * (1.0f / C) + 1e-6f);
  const float4* wr = (const float4*)w;
  float4 w0 = wr[t], w1 = wr[t + 256];
  u16* yr = y + (size_t)row * C;
  s16x4 o0, o1;
  o0[0] = (short)f2bf(v0.x * sc * w0.x); o0[1] = (short)f2bf(v0.y * sc * w0.y);
  o0[2] = (short)f2bf(v0.z * sc * w0.z); o0[3] = (short)f2bf(v0.w * sc * w0.w);
  o1[0] = (short)f2bf(v1.x * sc * w1.x); o1[1] = (short)f2bf(v1.y * sc * w1.y);
  o1[2] = (short)f2bf(v1.z * sc * w1.z); o1[3] = (short)f2bf(v1.w * sc * w1.w);
  *(s16x4*)(yr + t * 4) = o0;
  *(s16x4*)(yr + 1024 + t * 4) = o1;
}

// residual = a + sum(4 split-K partials) (fp32), x2 = bf16(rmsnorm(residual)*w)
__global__ __launch_bounds__(256)
void add_rmsnorm4_k(const float* __restrict__ a, const float* __restrict__ p,
                    const float* __restrict__ w, float* __restrict__ resid,
                    u16* __restrict__ y) {
  const int C = 2048;
  const size_t S = (size_t)1024 * 2048;
  const int row = blockIdx.x;
  const int t = threadIdx.x;
  const float4* ar = (const float4*)(a + (size_t)row * C);
  float4 v0 = ar[t], v1 = ar[t + 256];
#pragma unroll
  for (int s = 0; s < 4; ++s) {
    const float4* br = (const float4*)(p + s * S + (size_t)row * C);
    float4 u0 = br[t], u1 = br[t + 256];
    v0.x += u0.x; v0.y += u0.y; v0.z += u0.z; v0.w += u0.w;
    v1.x += u1.x; v1.y += u1.y; v1.z += u1.z; v1.w += u1.w;
  }
  float4* rr = (float4*)(resid + (size_t)row * C);
  rr[t] = v0; rr[t + 256] = v1;
  float ss = v0.x * v0.x + v0.y * v0.y + v0.z * v0.z + v0.w * v0.w +
             v1.x * v1.x + v1.y * v1.y + v1.z * v1.z + v1.w * v1.w;
  float tot = block_reduce_sum_256(ss);
  float sc = rsqrtf(tot * (1.0f / C) + 1e-6f);
  const float4* wr = (const float4*)w;
  float4 w0 = wr[t], w1 = wr[t + 256];
  u16* yr = y + (size_t)row * C;
  s16x4 o0, o1;
  o0[0] = (short)f2bf(v0.x * sc * w0.x); o0[1] = (short)f2bf(v0.y * sc * w0.y);
  o0[2] = (short)f2bf(v0.z * sc * w0.z); o0[3] = (short)f2bf(v0.w * sc * w0.w);
  o1[0] = (short)f2bf(v1.x * sc * w1.x); o1[1] = (short)f2bf(v1.y * sc * w1.y);
  o1[2] = (short)f2bf(v1.z * sc * w1.z); o1[3] = (short)f2bf(v1.w * sc * w1.w);
  *(s16x4*)(yr + t * 4) = o0;
  *(s16x4*)(yr + 1024 + t * 4) = o1;
}

// causal depthwise conv (K=4) + bias + silu -> bf16 h
__global__ __launch_bounds__(256)
void conv_silu_k(const float* __restrict__ proj, const float* __restrict__ cw,
                 const float* __restrict__ cb, u16* __restrict__ h) {
  const int Di = 4096, LD = 8192;
  int idx = blockIdx.x * 256 + threadIdx.x;
  int d = idx & (Di - 1);
  int l = idx >> 12;
  float4 w = *(const float4*)(cw + (size_t)d * 4);
  float acc = cb[d];
  int ls0 = l - 3;
  if (ls0 >= 0) acc += proj[(size_t)ls0 * LD + d] * w.x;
  if (ls0 + 1 >= 0) acc += proj[(size_t)(ls0 + 1) * LD + d] * w.y;
  if (ls0 + 2 >= 0) acc += proj[(size_t)(ls0 + 2) * LD + d] * w.z;
  acc += proj[(size_t)l * LD + d] * w.w;
  h[idx] = f2bf(acc * fast_sig(acc));
}

// three rmsnorms over the 160-wide ssm rows (summing 4 split-K partials):
// dt[128]->bf16, B[16], C[16]
__global__ __launch_bounds__(64)
void ssm_norm_k(const float* __restrict__ ssmp, const float* __restrict__ dtw,
                const float* __restrict__ bw, const float* __restrict__ cw,
                u16* __restrict__ dtn, float* __restrict__ Bn,
                float* __restrict__ Cn) {
  const size_t S = (size_t)1024 * 160;
  int l = blockIdx.x;
  int lane = threadIdx.x;
  float d0 = 0.f, d1 = 0.f, bv = 0.f, cv = 0.f;
#pragma unroll
  for (int s = 0; s < 4; ++s) {
    const float* r = ssmp + s * S + (size_t)l * 160;
    d0 += r[lane];
    d1 += r[lane + 64];
    if (lane < 16) {
      bv += r[128 + lane];
      cv += r[144 + lane];
    }
  }
  float sd = d0 * d0 + d1 * d1;
  float sb = bv * bv;
  float sc = cv * cv;
#pragma unroll
  for (int m = 32; m > 0; m >>= 1) {
    sd += __shfl_xor(sd, m, 64);
    sb += __shfl_xor(sb, m, 64);
    sc += __shfl_xor(sc, m, 64);
  }
  float scd = rsqrtf(sd * (1.f / 128.f) + 1e-6f);
  float scb = rsqrtf(sb * (1.f / 16.f) + 1e-6f);
  float scc = rsqrtf(sc * (1.f / 16.f) + 1e-6f);
  dtn[(size_t)l * 128 + lane] = f2bf(d0 * scd * dtw[lane]);
  dtn[(size_t)l * 128 + lane + 64] = f2bf(d1 * scd * dtw[lane + 64]);
  if (lane < 16) {
    Bn[(size_t)l * 16 + lane] = bv * scb * bw[lane];
    Cn[(size_t)l * 16 + lane] = cv * scc * cw[lane];
  }
}

// ---------------------------------------------------------------------------
// Chunked parallel scan over L=1024: NCH chunks of CHL.
#define NCH 32
#define CHL 32

__global__ __launch_bounds__(256)
void scan_p1(const float* __restrict__ dpre, const float* __restrict__ dtb,
             const u16* __restrict__ h, const float* __restrict__ Bn,
             const float* __restrict__ Amat,
             float* __restrict__ carryA, float* __restrict__ carryS) {
  const int Di = 4096;
  int chunk = blockIdx.x & (NCH - 1);
  int d = (blockIdx.x >> 5) * 256 + threadIdx.x;
  __shared__ float Bs[CHL * 16];
  for (int i = threadIdx.x; i < CHL * 16; i += 256)
    Bs[i] = Bn[(size_t)chunk * CHL * 16 + i];
  __syncthreads();
  float a[16];
#pragma unroll
  for (int q = 0; q < 4; ++q)
    *(float4*)&a[q * 4] = *(const float4*)(Amat + (size_t)d * 16 + q * 4);
  float bias = dtb[d];
  float s[16];
#pragma unroll
  for (int n = 0; n < 16; ++n) s[n] = 0.f;
  float sumdel = 0.f;
  int l0 = chunk * CHL;
#pragma unroll 4
  for (int j = 0; j < CHL; ++j) {
    int l = l0 + j;
    float del = fast_softplus(dpre[(size_t)l * Di + d] + bias);
    float hv = bf2f(h[(size_t)l * Di + d]);
    sumdel += del;
    float c = del * hv;
#pragma unroll
    for (int n = 0; n < 16; ++n) {
      float dA = __expf(del * a[n]);
      s[n] = dA * s[n] + c * Bs[j * 16 + n];
    }
  }
  size_t base = (size_t)chunk * 65536 + (size_t)d * 16;
#pragma unroll
  for (int n = 0; n < 16; ++n) {
    carryA[base + n] = __expf(sumdel * a[n]);
    carryS[base + n] = s[n];
  }
}

__global__ __launch_bounds__(256)
void scan_p2(const float* __restrict__ carryA, float* __restrict__ carryS) {
  int p = blockIdx.x * 256 + threadIdx.x;
  float cin = 0.f;
#pragma unroll
  for (int c = 0; c < NCH; ++c) {
    float av = carryA[(size_t)c * 65536 + p];
    float sv = carryS[(size_t)c * 65536 + p];
    float nx = av * cin + sv;
    carryS[(size_t)c * 65536 + p] = cin;
    cin = nx;
  }
}

__global__ __launch_bounds__(256)
void scan_p3(const float* __restrict__ dpre, const float* __restrict__ dtb,
             const u16* __restrict__ h, const float* __restrict__ Bn,
             const float* __restrict__ Cn, const float* __restrict__ Amat,
             const float* __restrict__ Dw, const float* __restrict__ proj,
             const float* __restrict__ carryS, u16* __restrict__ y) {
  const int Di = 4096;
  int chunk = blockIdx.x & (NCH - 1);
  int d = (blockIdx.x >> 5) * 256 + threadIdx.x;
  __shared__ float Bs[CHL * 16];
  __shared__ float Cs[CHL * 16];
  for (int i = threadIdx.x; i < CHL * 16; i += 256) {
    Bs[i] = Bn[(size_t)chunk * CHL * 16 + i];
    Cs[i] = Cn[(size_t)chunk * CHL * 16 + i];
  }
  __syncthreads();
  float a[16];
#pragma unroll
  for (int q = 0; q < 4; ++q)
    *(float4*)&a[q * 4] = *(const float4*)(Amat + (size_t)d * 16 + q * 4);
  float bias = dtb[d];
  float Dd = Dw[d];
  float s[16];
  size_t base = (size_t)chunk * 65536 + (size_t)d * 16;
#pragma unroll
  for (int q = 0; q < 4; ++q)
    *(float4*)&s[q * 4] = *(const float4*)(carryS + base + q * 4);
  int l0 = chunk * CHL;
#pragma unroll 2
  for (int j = 0; j < CHL; ++j) {
    int l = l0 + j;
    float del = fast_softplus(dpre[(size_t)l * Di + d] + bias);
    float hv = bf2f(h[(size_t)l * Di + d]);
    float c = del * hv;
    float p = 0.f;
#pragma unroll
    for (int n = 0; n < 16; ++n) {
      float dA = __expf(del * a[n]);
      s[n] = dA * s[n] + c * Bs[j * 16 + n];
      p += s[n] * Cs[j * 16 + n];
    }
    float g = proj[(size_t)l * 8192 + 4096 + d];
    float yv = p + hv * Dd;
    y[(size_t)l * Di + d] = f2bf(yv * g * fast_sig(g));
  }
}

// out += p0+p1+p2+p3 (split-K partials)
__global__ __launch_bounds__(256)
void add4_k(float* __restrict__ out, const float* __restrict__ p) {
  const size_t S = (size_t)1024 * 2048;
  int i = blockIdx.x * 256 + threadIdx.x;
  float4 a = ((const float4*)out)[i];
#pragma unroll
  for (int s = 0; s < 4; ++s) {
    float4 b = ((const float4*)(p + s * S))[i];
    a.x += b.x; a.y += b.y; a.z += b.z; a.w += b.w;
  }
  ((float4*)out)[i] = a;
}

// ---------------------------------------------------------------------------
extern "C" void kernel_launch(void* const* d_in, const int* in_sizes, int n_in,
                              void* d_out, int out_size, void* d_ws, size_t ws_size,
                              hipStream_t stream) {
  const float* hidden      = (const float*)d_in[0];
  const float* in_ln_w     = (const float*)d_in[1];
  const float* pre_ff_ln_w = (const float*)d_in[2];
  const float* in_proj_w   = (const float*)d_in[3];
  const float* conv_w      = (const float*)d_in[4];
  const float* conv_b      = (const float*)d_in[5];
  const float* x_proj_w    = (const float*)d_in[6];
  const float* dt_ln_w     = (const float*)d_in[7];
  const float* b_ln_w      = (const float*)d_in[8];
  const float* c_ln_w      = (const float*)d_in[9];
  const float* dt_proj_w   = (const float*)d_in[10];
  const float* dt_proj_b   = (const float*)d_in[11];
  const float* Amat        = (const float*)d_in[12];
  const float* Dw          = (const float*)d_in[13];
  const float* out_proj_w  = (const float*)d_in[14];
  const float* gate_up_w   = (const float*)d_in[15];
  const float* down_w      = (const float*)d_in[16];
  float* out = (float*)d_out;
  float* ws = (float*)d_ws;

  const int L = 1024, H = 2048, Di = 4096, F = 8192;

  // workspace (float-element offsets), peak ~106 MB
  u16*   wbuf   = (u16*)ws;                  // small-weight slab (bf16)
  float* carryA = ws + 2097152;              // NCH x 65536
  float* carryS = ws + 4194304;              // NCH x 65536
  float* proj   = ws + 8388608;              // L x 8192 fp32
  float* dpre   = ws + 16777216;             // L x 4096 fp32 (raw dt GEMM out)
  float* ssmp   = ws + 16777216;             // 4 x (L x 160) split-K partials
                                             // (in dpre hole; dead before dpre)
  u16*   hbuf   = (u16*)(ws + 20971520);     // L x 4096 bf16
  u16*   xnorm  = (u16*)(ws + 23068672);     // L x 2048 bf16
  u16*   dtn    = (u16*)(ws + 24281088);     // L x 128 bf16
  float* Bn     = ws + 24346624;             // L x 16
  float* Cn     = ws + 24363008;             // L x 16
  u16*   ybuf   = (u16*)(ws + 24379392);     // L x 4096 bf16
  float* mixp   = ws + 8388608;              // 4 x (L x 2048) split-K partials
  u16*   x2     = (u16*)(ws + 18874368);     // L x 2048 bf16
  u16*   sg     = (u16*)(ws + 8388608);      // L x 8192 bf16 (reuse proj)
  u16*   x3     = (u16*)(ws + 12582912);     // L x 8192 bf16 (reuse proj)
  float* ffp    = ws + 16777216;             // 4 x (L x 2048) split-K partials

  // 1. x_norm = bf16(rmsnorm(hidden))
  rmsnorm2048_k<<<L, 256, 0, stream>>>(hidden, in_ln_w, xnorm);
  // 2. proj = x_norm @ in_proj_w.T  (N=8192, K=2048)  [fused fp32-B, 2-deep]
  gemm128f<0, 1><<<dim3(64, 8), 256, 0, stream>>>(xnorm, in_proj_w, proj, nullptr, nullptr, L, 8192, 2048);
  // 3. h = bf16(silu(conv(proj[:, :Di]) + conv_b))
  conv_silu_k<<<(L * Di) / 256, 256, 0, stream>>>(proj, conv_w, conv_b, hbuf);
  // 4. ssm = h @ x_proj_w.T  (N=160 padded to 256, K=4096, split-K=4)
  f32_to_bf16_k<<<1024, 256, 0, stream>>>(x_proj_w, wbuf, 1048576, 655360);
  gemm2<64, 0, 4><<<dim3(4, 16, 4), 256, 0, stream>>>(hbuf, wbuf, ssmp, nullptr, nullptr, L, 160, 4096);
  // 5. split rmsnorms (sums the 4 ssm partials)
  ssm_norm_k<<<L, 64, 0, stream>>>(ssmp, dt_ln_w, b_ln_w, c_ln_w, dtn, Bn, Cn);
  // 6. delta_pre = dtn @ dt_proj_w.T  (N=4096, K=128)
  f32_to_bf16_k<<<512, 256, 0, stream>>>(dt_proj_w, wbuf, 524288, 524288);
  gemm2<128, 0, 1><<<dim3(32, 16), 256, 0, stream>>>(dtn, wbuf, dpre, nullptr, nullptr, L, 4096, 128);
  // 7-8. chunked scan (softplus fused, n-in-registers) -> ybuf (bf16)
  scan_p1<<<16 * NCH, 256, 0, stream>>>(dpre, dt_proj_b, hbuf, Bn, Amat, carryA, carryS);
  scan_p2<<<256, 256, 0, stream>>>(carryA, carryS);
  scan_p3<<<16 * NCH, 256, 0, stream>>>(dpre, dt_proj_b, hbuf, Bn, Cn, Amat, Dw, proj, carryS, ybuf);
  // 9. mix = y @ out_proj_w.T  (N=2048, K=4096)  [split-K=4 -> 512 blocks]
  gemm128f<0, 4><<<dim3(16, 8, 4), 256, 0, stream>>>(ybuf, out_proj_w, mixp, nullptr, nullptr, L, 2048, 4096);
  // 10. residual(out) = hidden + sum(mixp) ; x2 = bf16(rmsnorm(residual))
  add_rmsnorm4_k<<<L, 256, 0, stream>>>(hidden, mixp, pre_ff_ln_w, out, x2);
  // 11a. sg = bf16(silu(x2 @ gate_w.T))  (N=8192, K=2048)
  gemm128f<1, 1><<<dim3(64, 8), 256, 0, stream>>>(x2, gate_up_w, nullptr, sg, nullptr, L, 8192, 2048);
  // 11b. x3 = bf16((x2 @ up_w.T) * sg)
  gemm128f<2, 1><<<dim3(64, 8), 256, 0, stream>>>(x2, gate_up_w + 16777216, nullptr, x3, sg, L, 8192, 2048);
  // 13. ff = x3 @ down_w.T  (N=2048, K=8192)  [split-K=4 -> 512 blocks]
  gemm128f<0, 4><<<dim3(16, 8, 4), 256, 0, stream>>>(x3, down_w, ffp, nullptr, nullptr, L, 2048, 8192);
  // 14. out += sum(ffp)
  add4_k<<<(L * H / 4) / 256, 256, 0, stream>>>(out, ffp);
}

// Round 6
// 635.629 us; speedup vs baseline: 2.5712x; 2.5712x over previous
//
#include <hip/hip_runtime.h>
#include <math.h>

typedef unsigned short u16;
typedef __bf16 bf16x8 __attribute__((ext_vector_type(8)));
typedef short s16x8 __attribute__((ext_vector_type(8)));
typedef short s16x4 __attribute__((ext_vector_type(4)));
typedef float f32x4 __attribute__((ext_vector_type(4)));

__device__ __forceinline__ u16 f2bf(float f) {
  union { float f; unsigned u; } v; v.f = f;
  unsigned u = v.u;
  unsigned r = u + 0x7fffu + ((u >> 16) & 1u);
  return (u16)(r >> 16);
}
__device__ __forceinline__ float bf2f(u16 h) {
  union { unsigned u; float f; } v; v.u = ((unsigned)h) << 16;
  return v.f;
}
__device__ __forceinline__ float fast_softplus(float x) {
  return (x > 20.f) ? x : __logf(1.f + __expf(x));
}
__device__ __forceinline__ float fast_sig(float x) {
  return __builtin_amdgcn_rcpf(1.f + __expf(-x));
}
// HW packed f32->bf16 (RNE; same rounding as f2bf). No builtin on gfx950.
__device__ __forceinline__ unsigned cvtpk_bf16(float lo, float hi) {
  unsigned r;
  asm volatile("v_cvt_pk_bf16_f32 %0, %1, %2" : "=v"(r) : "v"(lo), "v"(hi));
  return r;
}

__device__ __forceinline__ void gld_lds16(const u16* g, u16* l) {
  __builtin_amdgcn_global_load_lds(
      (const __attribute__((address_space(1))) unsigned int*)g,
      (__attribute__((address_space(3))) unsigned int*)l, 16, 0, 0);
}

// ---------------------------------------------------------------------------
// fp32 -> bf16 weight conversion, zero-pads [n_valid, n)  (small weights only)
__global__ __launch_bounds__(256)
void f32_to_bf16_k(const float* __restrict__ src, u16* __restrict__ dst,
                   int n, int n_valid) {
  int i = (blockIdx.x * 256 + threadIdx.x) * 4;
  if (i >= n) return;
  s16x4 o;
  if (i + 3 < n_valid) {
    float4 v = *(const float4*)(src + i);
    o[0] = (short)f2bf(v.x); o[1] = (short)f2bf(v.y);
    o[2] = (short)f2bf(v.z); o[3] = (short)f2bf(v.w);
  } else {
    o[0] = 0; o[1] = 0; o[2] = 0; o[3] = 0;
  }
  *(s16x4*)(dst + i) = o;
}

// ---------------------------------------------------------------------------
// GEMM v2.2 (small-N shapes): C[M,N] = A[M,K](bf16) @ B[N,K](bf16)^T
// BM=64, BK=64, BN template {64,128}. Double-buffered LDS, one-tile-ahead
// prefetch with COUNTED vmcnt. XOR-swizzled LDS on DMA source + fragment read.
// SPLITK>1: blockIdx.z computes K-slice, writes partial at z*M*Nc (MODE 0 only).
template <int BN, int MODE, int SPLITK>
__global__ __launch_bounds__(256)
void gemm2(const u16* __restrict__ A, const u16* __restrict__ B,
           float* __restrict__ C, u16* __restrict__ Cb,
           const u16* __restrict__ aux, int M, int Nc, int K) {
  constexpr int NJ = BN / 32;
  constexpr int BISS = BN / 32;
  constexpr int ABUF = 64 * 64;
  constexpr int BBUF = BN * 64;
  __shared__ __align__(16) u16 As[2 * ABUF];
  __shared__ __align__(16) u16 Bs[2 * BBUF];
  const int tid = threadIdx.x;
  const int tm0 = blockIdx.y * 64;
  const int tn0 = blockIdx.x * BN;
  const int kslice = K / SPLITK;
  const int k0 = blockIdx.z * kslice;
  const int wave = tid >> 6;
  const int lane = tid & 63;
  const int wm = (wave >> 1) * 32;
  const int wn = (wave & 1) * (BN / 2);
  const int frow = lane & 15;
  const int fc = lane >> 4;
  const int rmask = frow & 7;

  const int r0 = tid >> 3;
  const int csw = (((tid & 7) ^ (r0 & 7)) << 3);
  const u16* gA = A + (size_t)(tm0 + r0) * K + k0 + csw;
  const u16* gB = B + (size_t)(tn0 + r0) * K + k0 + csw;
  u16* lA = &As[tid * 8];
  u16* lB = &Bs[tid * 8];

  f32x4 acc[2][NJ];
  f32x4 zero = {0.f, 0.f, 0.f, 0.f};
#pragma unroll
  for (int i = 0; i < 2; ++i)
#pragma unroll
    for (int j = 0; j < NJ; ++j) acc[i][j] = zero;

  auto stage = [&](int bi) {
    gld_lds16(gA, lA + bi * ABUF);
    gld_lds16(gA + (size_t)32 * K, lA + bi * ABUF + 2048);
#pragma unroll
    for (int b = 0; b < BISS; ++b)
      gld_lds16(gB + (size_t)32 * b * K, lB + bi * BBUF + b * 2048);
    gA += 64; gB += 64;
  };

  stage(0);
  const int nt = kslice >> 6;
  int buf = 0;
  for (int kt = 0; kt < nt; ++kt) {
    const int nb = buf ^ 1;
    if (kt + 1 < nt) {
      stage(nb);
      if constexpr (BN == 64) asm volatile("s_waitcnt vmcnt(4)" ::: "memory");
      else                    asm volatile("s_waitcnt vmcnt(6)" ::: "memory");
    } else {
      asm volatile("s_waitcnt vmcnt(0)" ::: "memory");
    }
    __builtin_amdgcn_s_barrier();
    __builtin_amdgcn_sched_barrier(0);
    const int ao = buf * ABUF, bo = buf * BBUF;
#pragma unroll
    for (int s = 0; s < 2; ++s) {
      bf16x8 af[2], bfr[NJ];
#pragma unroll
      for (int i = 0; i < 2; ++i) {
        int addr = ao + (wm + i * 16 + frow) * 64 + (((s * 4 + fc) ^ rmask) << 3);
        af[i] = __builtin_bit_cast(bf16x8, *(const s16x8*)&As[addr]);
      }
#pragma unroll
      for (int j = 0; j < NJ; ++j) {
        int addr = bo + (wn + j * 16 + frow) * 64 + (((s * 4 + fc) ^ rmask) << 3);
        bfr[j] = __builtin_bit_cast(bf16x8, *(const s16x8*)&Bs[addr]);
      }
#pragma unroll
      for (int i = 0; i < 2; ++i)
#pragma unroll
        for (int j = 0; j < NJ; ++j)
          acc[i][j] = __builtin_amdgcn_mfma_f32_16x16x32_bf16(af[i], bfr[j], acc[i][j], 0, 0, 0);
    }
    __builtin_amdgcn_s_barrier();
    buf = nb;
  }
  const int ccol = lane & 15;
  const int crow = (lane >> 4) * 4;
  float* Cp = C + (size_t)blockIdx.z * ((size_t)M * Nc);
#pragma unroll
  for (int i = 0; i < 2; ++i) {
#pragma unroll
    for (int j = 0; j < NJ; ++j) {
      int gn = tn0 + wn + j * 16 + ccol;
      if (gn < Nc) {
        size_t base = (size_t)(tm0 + wm + i * 16 + crow) * Nc + gn;
#pragma unroll
        for (int r = 0; r < 4; ++r) {
          float c = acc[i][j][r];
          size_t idx = base + (size_t)r * Nc;
          if (MODE == 0) {
            Cp[idx] = c;
          } else if (MODE == 1) {
            Cb[idx] = f2bf(c * fast_sig(c));
          } else {
            Cb[idx] = f2bf(c * bf2f(aux[idx]));
          }
        }
      }
    }
  }
}

// ---------------------------------------------------------------------------
// GEMM v4.2: BM=128, BN=128, BK=64, 4 waves x 64x64 (4x4 frags), fused
// fp32->bf16 B conversion, TWO-DEEP B register pipeline with STATIC indexing
// (rule #20: named brg0/brg1 + K-loop unrolled by 2 so every register-set
// reference is compile-time; R5's brg[kt&1] spilled the pipeline to scratch).
// Steady-state per step t: issue B-loads(t+2) + A-DMA(t+1); vmcnt(12) retires
// exactly {A(t), B(t+1)} (both >= 1 full iteration old); barrier; MFMA(t);
// cvt+ds_write of B(t+1) (loads already retired -> stall-free); lgkmcnt(0);
// barrier. vmcnt never drains to 0 mid-loop (tails: vmcnt(4)/vmcnt(0)).
// Requires nt = kslice/64 even and >= 2 (true for all shapes used: 16/32).
template <int MODE, int SPLITK>
__global__ __launch_bounds__(256)
void gemm128f(const u16* __restrict__ A, const float* __restrict__ Bw,
              float* __restrict__ C, u16* __restrict__ Cb,
              const u16* __restrict__ aux, int M, int Nc, int K) {
  __shared__ __align__(16) u16 As[2 * 8192];   // 32 KB
  __shared__ __align__(16) u16 Bs[2 * 8192];   // 32 KB
  const int tid = threadIdx.x;
  const int tm0 = blockIdx.y * 128;
  const int tn0 = blockIdx.x * 128;
  const int kslice = K / SPLITK;
  const int k0 = blockIdx.z * kslice;
  const int wave = tid >> 6;
  const int lane = tid & 63;
  const int wm = (wave >> 1) * 64;
  const int wn = (wave & 1) * 64;
  const int frow = lane & 15;
  const int fc = lane >> 4;
  const int rmask = frow & 7;

  const int r0 = tid >> 3;                        // LDS row (of 32-row group)
  const int csw = (((tid & 7) ^ (r0 & 7)) << 3);  // swizzled chunk offset
  // A: DMA with source-side swizzle, linear LDS dest
  const u16* gA = A + (size_t)(tm0 + r0) * K + k0 + csw;
  u16* lA = &As[tid * 8];
  // B: linear fp32 global source; swizzle applied on the ds_write address
  const float* gBf = Bw + (size_t)(tn0 + r0) * K + k0 + (tid & 7) * 8;
  u16* lBw = &Bs[r0 * 64 + csw];

  f32x4 acc[4][4];
  f32x4 zero = {0.f, 0.f, 0.f, 0.f};
#pragma unroll
  for (int i = 0; i < 4; ++i)
#pragma unroll
    for (int j = 0; j < 4; ++j) acc[i][j] = zero;

  float4 brg0[4][2];   // B tile register set 0 (even tiles)
  float4 brg1[4][2];   // B tile register set 1 (odd tiles)

#define LOADB(RG) do {                                  \
    _Pragma("unroll")                                   \
    for (int b = 0; b < 4; ++b) {                       \
      const float* p = gBf + (size_t)(32 * b) * K;      \
      RG[b][0] = *(const float4*)p;                     \
      RG[b][1] = *(const float4*)(p + 4);               \
    }                                                   \
    gBf += 64;                                          \
  } while (0)

#define WRITEB(RG, BI) do {                             \
    _Pragma("unroll")                                   \
    for (int b = 0; b < 4; ++b) {                       \
      uint4 o;                                          \
      o.x = cvtpk_bf16(RG[b][0].x, RG[b][0].y);         \
      o.y = cvtpk_bf16(RG[b][0].z, RG[b][0].w);         \
      o.z = cvtpk_bf16(RG[b][1].x, RG[b][1].y);         \
      o.w = cvtpk_bf16(RG[b][1].z, RG[b][1].w);         \
      *(uint4*)(lBw + (BI) * 8192 + b * 2048) = o;      \
    }                                                   \
  } while (0)

  auto stageA = [&](int bi) {
#pragma unroll
    for (int b = 0; b < 4; ++b)
      gld_lds16(gA + (size_t)(32 * b) * K, lA + bi * 8192 + b * 2048);
    gA += 64;
  };
  auto compute = [&](int boff) {
#pragma unroll
    for (int s = 0; s < 2; ++s) {
      bf16x8 af[4], bfr[4];
#pragma unroll
      for (int i = 0; i < 4; ++i) {
        int addr = boff + (wm + i * 16 + frow) * 64 + (((s * 4 + fc) ^ rmask) << 3);
        af[i] = __builtin_bit_cast(bf16x8, *(const s16x8*)&As[addr]);
      }
#pragma unroll
      for (int j = 0; j < 4; ++j) {
        int addr = boff + (wn + j * 16 + frow) * 64 + (((s * 4 + fc) ^ rmask) << 3);
        bfr[j] = __builtin_bit_cast(bf16x8, *(const s16x8*)&Bs[addr]);
      }
#pragma unroll
      for (int i = 0; i < 4; ++i)
#pragma unroll
        for (int j = 0; j < 4; ++j)
          acc[i][j] = __builtin_amdgcn_mfma_f32_16x16x32_bf16(af[i], bfr[j], acc[i][j], 0, 0, 0);
    }
  };

  const int nt = kslice >> 6;   // even, >= 2 for all shapes used here
  // prologue: B(0)->brg0, A(0)->buf0, B(1)->brg1; cvt+write B(0) into buf0
  // (compiler-inserted vmcnt retires exactly B(0)'s 8 loads).
  LOADB(brg0);
  stageA(0);
  LOADB(brg1);
  WRITEB(brg0, 0);
  asm volatile("s_waitcnt lgkmcnt(0)" ::: "memory");

  for (int kt = 0; kt < nt; kt += 2) {
    // ---- even step: tile kt (buf0); prefetch B(kt+2)->brg0, A(kt+1)->buf1
    if (kt + 2 < nt) LOADB(brg0);
    stageA(1);                               // kt+1 < nt always (kt <= nt-2)
    if (kt + 2 < nt) asm volatile("s_waitcnt vmcnt(12)" ::: "memory");
    else             asm volatile("s_waitcnt vmcnt(4)"  ::: "memory");
    __builtin_amdgcn_s_barrier();            // B1: A(kt)+B(kt) ready in LDS
    __builtin_amdgcn_sched_barrier(0);
    compute(0);
    WRITEB(brg1, 1);                         // tile kt+1 -> buf1 (stall-free)
    asm volatile("s_waitcnt lgkmcnt(0)" ::: "memory");
    __builtin_amdgcn_sched_barrier(0);
    __builtin_amdgcn_s_barrier();            // B2
    // ---- odd step: tile kt+1 (buf1); prefetch B(kt+3)->brg1, A(kt+2)->buf0
    if (kt + 3 < nt) LOADB(brg1);
    if (kt + 2 < nt) stageA(0);
    if (kt + 3 < nt)      asm volatile("s_waitcnt vmcnt(12)" ::: "memory");
    else if (kt + 2 < nt) asm volatile("s_waitcnt vmcnt(4)"  ::: "memory");
    else                  asm volatile("s_waitcnt vmcnt(0)"  ::: "memory");
    __builtin_amdgcn_s_barrier();            // B1
    __builtin_amdgcn_sched_barrier(0);
    compute(8192);
    if (kt + 2 < nt) {
      WRITEB(brg0, 0);                       // tile kt+2 -> buf0 (stall-free)
      asm volatile("s_waitcnt lgkmcnt(0)" ::: "memory");
      __builtin_amdgcn_sched_barrier(0);
    }
    __builtin_amdgcn_s_barrier();            // B2
  }
#undef LOADB
#undef WRITEB

  const int ccol = lane & 15;
  const int crow = (lane >> 4) * 4;
  float* Cp = C + (size_t)blockIdx.z * ((size_t)M * Nc);
#pragma unroll
  for (int i = 0; i < 4; ++i) {
#pragma unroll
    for (int j = 0; j < 4; ++j) {
      int gn = tn0 + wn + j * 16 + ccol;
      size_t base = (size_t)(tm0 + wm + i * 16 + crow) * Nc + gn;
#pragma unroll
      for (int r = 0; r < 4; ++r) {
        float c = acc[i][j][r];
        size_t idx = base + (size_t)r * Nc;
        if (MODE == 0) {
          Cp[idx] = c;
        } else if (MODE == 1) {
          Cb[idx] = f2bf(c * fast_sig(c));
        } else {
          Cb[idx] = f2bf(c * bf2f(aux[idx]));
        }
      }
    }
  }
}

// ---------------------------------------------------------------------------
__device__ inline float block_reduce_sum_256(float v) {
  __shared__ float red[4];
  int lane = threadIdx.x & 63, wave = threadIdx.x >> 6;
#pragma unroll
  for (int m = 32; m > 0; m >>= 1) v += __shfl_xor(v, m, 64);
  if (lane == 0) red[wave] = v;
  __syncthreads();
  return red[0] + red[1] + red[2] + red[3];
}

// rmsnorm over C=2048 -> bf16 out
__global__ __launch_bounds__(256)
void rmsnorm2048_k(const float* __restrict__ x, const float* __restrict__ w,
                   u16* __restrict__ y) {
  const int C = 2048;
  const int row = blockIdx.x;
  const int t = threadIdx.x;
  const float4* xr = (const float4*)(x + (size_t)row * C);
  float4 v0 = xr[t];
  float4 v1 = xr[t + 256];
  float ss = v0.x * v0.x + v0.y * v0.y + v0.z * v0.z + v0.w * v0.w +
             v1.x * v1.x + v1.y * v1.y + v1.z * v1.z + v1.w * v1.w;
  float tot = block_reduce_sum_256(ss);
  float sc = rsqrtf(tot * (1.0f / C) + 1e-6f);
  const float4* wr = (const float4*)w;
  float4 w0 = wr[t], w1 = wr[t + 256];
  u16* yr = y + (size_t)row * C;
  s16x4 o0, o1;
  o0[0] = (short)f2bf(v0.x * sc * w0.x); o0[1] = (short)f2bf(v0.y * sc * w0.y);
  o0[2] = (short)f2bf(v0.z * sc * w0.z); o0[3] = (short)f2bf(v0.w * sc * w0.w);
  o1[0] = (short)f2bf(v1.x * sc * w1.x); o1[1] = (short)f2bf(v1.y * sc * w1.y);
  o1[2] = (short)f2bf(v1.z * sc * w1.z); o1[3] = (short)f2bf(v1.w * sc * w1.w);
  *(s16x4*)(yr + t * 4) = o0;
  *(s16x4*)(yr + 1024 + t * 4) = o1;
}

// residual = a + sum(4 split-K partials) (fp32), x2 = bf16(rmsnorm(residual)*w)
__global__ __launch_bounds__(256)
void add_rmsnorm4_k(const float* __restrict__ a, const float* __restrict__ p,
                    const float* __restrict__ w, float* __restrict__ resid,
                    u16* __restrict__ y) {
  const int C = 2048;
  const size_t S = (size_t)1024 * 2048;
  const int row = blockIdx.x;
  const int t = threadIdx.x;
  const float4* ar = (const float4*)(a + (size_t)row * C);
  float4 v0 = ar[t], v1 = ar[t + 256];
#pragma unroll
  for (int s = 0; s < 4; ++s) {
    const float4* br = (const float4*)(p + s * S + (size_t)row * C);
    float4 u0 = br[t], u1 = br[t + 256];
    v0.x += u0.x; v0.y += u0.y; v0.z += u0.z; v0.w += u0.w;
    v1.x += u1.x; v1.y += u1.y; v1.z += u1.z; v1.w += u1.w;
  }
  float4* rr = (float4*)(resid + (size_t)row * C);
  rr[t] = v0; rr[t + 256] = v1;
  float ss = v0.x * v0.x + v0.y * v0.y + v0.z * v0.z + v0.w * v0.w +
             v1.x * v1.x + v1.y * v1.y + v1.z * v1.z + v1.w * v1.w;
  float tot = block_reduce_sum_256(ss);
  float sc = rsqrtf(tot * (1.0f / C) + 1e-6f);
  const float4* wr = (const float4*)w;
  float4 w0 = wr[t], w1 = wr[t + 256];
  u16* yr = y + (size_t)row * C;
  s16x4 o0, o1;
  o0[0] = (short)f2bf(v0.x * sc * w0.x); o0[1] = (short)f2bf(v0.y * sc * w0.y);
  o0[2] = (short)f2bf(v0.z * sc * w0.z); o0[3] = (short)f2bf(v0.w * sc * w0.w);
  o1[0] = (short)f2bf(v1.x * sc * w1.x); o1[1] = (short)f2bf(v1.y * sc * w1.y);
  o1[2] = (short)f2bf(v1.z * sc * w1.z); o1[3] = (short)f2bf(v1.w * sc * w1.w);
  *(s16x4*)(yr + t * 4) = o0;
  *(s16x4*)(yr + 1024 + t * 4) = o1;
}

// causal depthwise conv (K=4) + bias + silu -> bf16 h
__global__ __launch_bounds__(256)
void conv_silu_k(const float* __restrict__ proj, const float* __restrict__ cw,
                 const float* __restrict__ cb, u16* __restrict__ h) {
  const int Di = 4096, LD = 8192;
  int idx = blockIdx.x * 256 + threadIdx.x;
  int d = idx & (Di - 1);
  int l = idx >> 12;
  float4 w = *(const float4*)(cw + (size_t)d * 4);
  float acc = cb[d];
  int ls0 = l - 3;
  if (ls0 >= 0) acc += proj[(size_t)ls0 * LD + d] * w.x;
  if (ls0 + 1 >= 0) acc += proj[(size_t)(ls0 + 1) * LD + d] * w.y;
  if (ls0 + 2 >= 0) acc += proj[(size_t)(ls0 + 2) * LD + d] * w.z;
  acc += proj[(size_t)l * LD + d] * w.w;
  h[idx] = f2bf(acc * fast_sig(acc));
}

// three rmsnorms over the 160-wide ssm rows (summing 4 split-K partials):
// dt[128]->bf16, B[16], C[16]
__global__ __launch_bounds__(64)
void ssm_norm_k(const float* __restrict__ ssmp, const float* __restrict__ dtw,
                const float* __restrict__ bw, const float* __restrict__ cw,
                u16* __restrict__ dtn, float* __restrict__ Bn,
                float* __restrict__ Cn) {
  const size_t S = (size_t)1024 * 160;
  int l = blockIdx.x;
  int lane = threadIdx.x;
  float d0 = 0.f, d1 = 0.f, bv = 0.f, cv = 0.f;
#pragma unroll
  for (int s = 0; s < 4; ++s) {
    const float* r = ssmp + s * S + (size_t)l * 160;
    d0 += r[lane];
    d1 += r[lane + 64];
    if (lane < 16) {
      bv += r[128 + lane];
      cv += r[144 + lane];
    }
  }
  float sd = d0 * d0 + d1 * d1;
  float sb = bv * bv;
  float sc = cv * cv;
#pragma unroll
  for (int m = 32; m > 0; m >>= 1) {
    sd += __shfl_xor(sd, m, 64);
    sb += __shfl_xor(sb, m, 64);
    sc += __shfl_xor(sc, m, 64);
  }
  float scd = rsqrtf(sd * (1.f / 128.f) + 1e-6f);
  float scb = rsqrtf(sb * (1.f / 16.f) + 1e-6f);
  float scc = rsqrtf(sc * (1.f / 16.f) + 1e-6f);
  dtn[(size_t)l * 128 + lane] = f2bf(d0 * scd * dtw[lane]);
  dtn[(size_t)l * 128 + lane + 64] = f2bf(d1 * scd * dtw[lane + 64]);
  if (lane < 16) {
    Bn[(size_t)l * 16 + lane] = bv * scb * bw[lane];
    Cn[(size_t)l * 16 + lane] = cv * scc * cw[lane];
  }
}

// ---------------------------------------------------------------------------
// Chunked parallel scan over L=1024: NCH chunks of CHL.
#define NCH 32
#define CHL 32

__global__ __launch_bounds__(256)
void scan_p1(const float* __restrict__ dpre, const float* __restrict__ dtb,
             const u16* __restrict__ h, const float* __restrict__ Bn,
             const float* __restrict__ Amat,
             float* __restrict__ carryA, float* __restrict__ carryS) {
  const int Di = 4096;
  int chunk = blockIdx.x & (NCH - 1);
  int d = (blockIdx.x >> 5) * 256 + threadIdx.x;
  __shared__ float Bs[CHL * 16];
  for (int i = threadIdx.x; i < CHL * 16; i += 256)
    Bs[i] = Bn[(size_t)chunk * CHL * 16 + i];
  __syncthreads();
  float a[16];
#pragma unroll
  for (int q = 0; q < 4; ++q)
    *(float4*)&a[q * 4] = *(const float4*)(Amat + (size_t)d * 16 + q * 4);
  float bias = dtb[d];
  float s[16];
#pragma unroll
  for (int n = 0; n < 16; ++n) s[n] = 0.f;
  float sumdel = 0.f;
  int l0 = chunk * CHL;
#pragma unroll 4
  for (int j = 0; j < CHL; ++j) {
    int l = l0 + j;
    float del = fast_softplus(dpre[(size_t)l * Di + d] + bias);
    float hv = bf2f(h[(size_t)l * Di + d]);
    sumdel += del;
    float c = del * hv;
#pragma unroll
    for (int n = 0; n < 16; ++n) {
      float dA = __expf(del * a[n]);
      s[n] = dA * s[n] + c * Bs[j * 16 + n];
    }
  }
  size_t base = (size_t)chunk * 65536 + (size_t)d * 16;
#pragma unroll
  for (int n = 0; n < 16; ++n) {
    carryA[base + n] = __expf(sumdel * a[n]);
    carryS[base + n] = s[n];
  }
}

__global__ __launch_bounds__(256)
void scan_p2(const float* __restrict__ carryA, float* __restrict__ carryS) {
  int p = blockIdx.x * 256 + threadIdx.x;
  float cin = 0.f;
#pragma unroll
  for (int c = 0; c < NCH; ++c) {
    float av = carryA[(size_t)c * 65536 + p];
    float sv = carryS[(size_t)c * 65536 + p];
    float nx = av * cin + sv;
    carryS[(size_t)c * 65536 + p] = cin;
    cin = nx;
  }
}

__global__ __launch_bounds__(256)
void scan_p3(const float* __restrict__ dpre, const float* __restrict__ dtb,
             const u16* __restrict__ h, const float* __restrict__ Bn,
             const float* __restrict__ Cn, const float* __restrict__ Amat,
             const float* __restrict__ Dw, const float* __restrict__ proj,
             const float* __restrict__ carryS, u16* __restrict__ y) {
  const int Di = 4096;
  int chunk = blockIdx.x & (NCH - 1);
  int d = (blockIdx.x >> 5) * 256 + threadIdx.x;
  __shared__ float Bs[CHL * 16];
  __shared__ float Cs[CHL * 16];
  for (int i = threadIdx.x; i < CHL * 16; i += 256) {
    Bs[i] = Bn[(size_t)chunk * CHL * 16 + i];
    Cs[i] = Cn[(size_t)chunk * CHL * 16 + i];
  }
  __syncthreads();
  float a[16];
#pragma unroll
  for (int q = 0; q < 4; ++q)
    *(float4*)&a[q * 4] = *(const float4*)(Amat + (size_t)d * 16 + q * 4);
  float bias = dtb[d];
  float Dd = Dw[d];
  float s[16];
  size_t base = (size_t)chunk * 65536 + (size_t)d * 16;
#pragma unroll
  for (int q = 0; q < 4; ++q)
    *(float4*)&s[q * 4] = *(const float4*)(carryS + base + q * 4);
  int l0 = chunk * CHL;
#pragma unroll 2
  for (int j = 0; j < CHL; ++j) {
    int l = l0 + j;
    float del = fast_softplus(dpre[(size_t)l * Di + d] + bias);
    float hv = bf2f(h[(size_t)l * Di + d]);
    float c = del * hv;
    float p = 0.f;
#pragma unroll
    for (int n = 0; n < 16; ++n) {
      float dA = __expf(del * a[n]);
      s[n] = dA * s[n] + c * Bs[j * 16 + n];
      p += s[n] * Cs[j * 16 + n];
    }
    float g = proj[(size_t)l * 8192 + 4096 + d];
    float yv = p + hv * Dd;
    y[(size_t)l * Di + d] = f2bf(yv * g * fast_sig(g));
  }
}

// out += p0+p1+p2+p3 (split-K partials)
__global__ __launch_bounds__(256)
void add4_k(float* __restrict__ out, const float* __restrict__ p) {
  const size_t S = (size_t)1024 * 2048;
  int i = blockIdx.x * 256 + threadIdx.x;
  float4 a = ((const float4*)out)[i];
#pragma unroll
  for (int s = 0; s < 4; ++s) {
    float4 b = ((const float4*)(p + s * S))[i];
    a.x += b.x; a.y += b.y; a.z += b.z; a.w += b.w;
  }
  ((float4*)out)[i] = a;
}

// ---------------------------------------------------------------------------
extern "C" void kernel_launch(void* const* d_in, const int* in_sizes, int n_in,
                              void* d_out, int out_size, void* d_ws, size_t ws_size,
                              hipStream_t stream) {
  const float* hidden      = (const float*)d_in[0];
  const float* in_ln_w     = (const float*)d_in[1];
  const float* pre_ff_ln_w = (const float*)d_in[2];
  const float* in_proj_w   = (const float*)d_in[3];
  const float* conv_w      = (const float*)d_in[4];
  const float* conv_b      = (const float*)d_in[5];
  const float* x_proj_w    = (const float*)d_in[6];
  const float* dt_ln_w     = (const float*)d_in[7];
  const float* b_ln_w      = (const float*)d_in[8];
  const float* c_ln_w      = (const float*)d_in[9];
  const float* dt_proj_w   = (const float*)d_in[10];
  const float* dt_proj_b   = (const float*)d_in[11];
  const float* Amat        = (const float*)d_in[12];
  const float* Dw          = (const float*)d_in[13];
  const float* out_proj_w  = (const float*)d_in[14];
  const float* gate_up_w   = (const float*)d_in[15];
  const float* down_w      = (const float*)d_in[16];
  float* out = (float*)d_out;
  float* ws = (float*)d_ws;

  const int L = 1024, H = 2048, Di = 4096, F = 8192;

  // workspace (float-element offsets), peak ~106 MB
  u16*   wbuf   = (u16*)ws;                  // small-weight slab (bf16)
  float* carryA = ws + 2097152;              // NCH x 65536
  float* carryS = ws + 4194304;              // NCH x 65536
  float* proj   = ws + 8388608;              // L x 8192 fp32
  float* dpre   = ws + 16777216;             // L x 4096 fp32 (raw dt GEMM out)
  float* ssmp   = ws + 16777216;             // 4 x (L x 160) split-K partials
                                             // (in dpre hole; dead before dpre)
  u16*   hbuf   = (u16*)(ws + 20971520);     // L x 4096 bf16
  u16*   xnorm  = (u16*)(ws + 23068672);     // L x 2048 bf16
  u16*   dtn    = (u16*)(ws + 24281088);     // L x 128 bf16
  float* Bn     = ws + 24346624;             // L x 16
  float* Cn     = ws + 24363008;             // L x 16
  u16*   ybuf   = (u16*)(ws + 24379392);     // L x 4096 bf16
  float* mixp   = ws + 8388608;              // 4 x (L x 2048) split-K partials
  u16*   x2     = (u16*)(ws + 18874368);     // L x 2048 bf16
  u16*   sg     = (u16*)(ws + 8388608);      // L x 8192 bf16 (reuse proj)
  u16*   x3     = (u16*)(ws + 12582912);     // L x 8192 bf16 (reuse proj)
  float* ffp    = ws + 16777216;             // 4 x (L x 2048) split-K partials

  // 1. x_norm = bf16(rmsnorm(hidden))
  rmsnorm2048_k<<<L, 256, 0, stream>>>(hidden, in_ln_w, xnorm);
  // 2. proj = x_norm @ in_proj_w.T  (N=8192, K=2048)  [fused fp32-B, 2-deep]
  gemm128f<0, 1><<<dim3(64, 8), 256, 0, stream>>>(xnorm, in_proj_w, proj, nullptr, nullptr, L, 8192, 2048);
  // 3. h = bf16(silu(conv(proj[:, :Di]) + conv_b))
  conv_silu_k<<<(L * Di) / 256, 256, 0, stream>>>(proj, conv_w, conv_b, hbuf);
  // 4. ssm = h @ x_proj_w.T  (N=160 padded to 256, K=4096, split-K=4)
  f32_to_bf16_k<<<1024, 256, 0, stream>>>(x_proj_w, wbuf, 1048576, 655360);
  gemm2<64, 0, 4><<<dim3(4, 16, 4), 256, 0, stream>>>(hbuf, wbuf, ssmp, nullptr, nullptr, L, 160, 4096);
  // 5. split rmsnorms (sums the 4 ssm partials)
  ssm_norm_k<<<L, 64, 0, stream>>>(ssmp, dt_ln_w, b_ln_w, c_ln_w, dtn, Bn, Cn);
  // 6. delta_pre = dtn @ dt_proj_w.T  (N=4096, K=128)
  f32_to_bf16_k<<<512, 256, 0, stream>>>(dt_proj_w, wbuf, 524288, 524288);
  gemm2<128, 0, 1><<<dim3(32, 16), 256, 0, stream>>>(dtn, wbuf, dpre, nullptr, nullptr, L, 4096, 128);
  // 7-8. chunked scan (softplus fused, n-in-registers) -> ybuf (bf16)
  scan_p1<<<16 * NCH, 256, 0, stream>>>(dpre, dt_proj_b, hbuf, Bn, Amat, carryA, carryS);
  scan_p2<<<256, 256, 0, stream>>>(carryA, carryS);
  scan_p3<<<16 * NCH, 256, 0, stream>>>(dpre, dt_proj_b, hbuf, Bn, Cn, Amat, Dw, proj, carryS, ybuf);
  // 9. mix = y @ out_proj_w.T  (N=2048, K=4096)  [split-K=4 -> 512 blocks]
  gemm128f<0, 4><<<dim3(16, 8, 4), 256, 0, stream>>>(ybuf, out_proj_w, mixp, nullptr, nullptr, L, 2048, 4096);
  // 10. residual(out) = hidden + sum(mixp) ; x2 = bf16(rmsnorm(residual))
  add_rmsnorm4_k<<<L, 256, 0, stream>>>(hidden, mixp, pre_ff_ln_w, out, x2);
  // 11a. sg = bf16(silu(x2 @ gate_w.T))  (N=8192, K=2048)
  gemm128f<1, 1><<<dim3(64, 8), 256, 0, stream>>>(x2, gate_up_w, nullptr, sg, nullptr, L, 8192, 2048);
  // 11b. x3 = bf16((x2 @ up_w.T) * sg)
  gemm128f<2, 1><<<dim3(64, 8), 256, 0, stream>>>(x2, gate_up_w + 16777216, nullptr, x3, sg, L, 8192, 2048);
  // 13. ff = x3 @ down_w.T  (N=2048, K=8192)  [split-K=4 -> 512 blocks]
  gemm128f<0, 4><<<dim3(16, 8, 4), 256, 0, stream>>>(x3, down_w, ffp, nullptr, nullptr, L, 2048, 8192);
  // 14. out += sum(ffp)
  add4_k<<<(L * H / 4) / 256, 256, 0, stream>>>(out, ffp);
}

// Round 7
// 631.840 us; speedup vs baseline: 2.5866x; 1.0060x over previous
//
#include <hip/hip_runtime.h>
#include <math.h>

typedef unsigned short u16;
typedef __bf16 bf16x8 __attribute__((ext_vector_type(8)));
typedef short s16x8 __attribute__((ext_vector_type(8)));
typedef short s16x4 __attribute__((ext_vector_type(4)));
typedef float f32x4 __attribute__((ext_vector_type(4)));

__device__ __forceinline__ u16 f2bf(float f) {
  union { float f; unsigned u; } v; v.f = f;
  unsigned u = v.u;
  unsigned r = u + 0x7fffu + ((u >> 16) & 1u);
  return (u16)(r >> 16);
}
__device__ __forceinline__ float bf2f(u16 h) {
  union { unsigned u; float f; } v; v.u = ((unsigned)h) << 16;
  return v.f;
}
__device__ __forceinline__ float fast_softplus(float x) {
  return (x > 20.f) ? x : __logf(1.f + __expf(x));
}
__device__ __forceinline__ float fast_sig(float x) {
  return __builtin_amdgcn_rcpf(1.f + __expf(-x));
}
// HW packed f32->bf16 (RNE; same rounding as f2bf). No builtin on gfx950.
__device__ __forceinline__ unsigned cvtpk_bf16(float lo, float hi) {
  unsigned r;
  asm volatile("v_cvt_pk_bf16_f32 %0, %1, %2" : "=v"(r) : "v"(lo), "v"(hi));
  return r;
}

__device__ __forceinline__ void gld_lds16(const u16* g, u16* l) {
  __builtin_amdgcn_global_load_lds(
      (const __attribute__((address_space(1))) unsigned int*)g,
      (__attribute__((address_space(3))) unsigned int*)l, 16, 0, 0);
}

// ---------------------------------------------------------------------------
// fp32 -> bf16 weight conversion, zero-pads [n_valid, n)  (small weights only)
__global__ __launch_bounds__(256)
void f32_to_bf16_k(const float* __restrict__ src, u16* __restrict__ dst,
                   int n, int n_valid) {
  int i = (blockIdx.x * 256 + threadIdx.x) * 4;
  if (i >= n) return;
  s16x4 o;
  if (i + 3 < n_valid) {
    float4 v = *(const float4*)(src + i);
    o[0] = (short)f2bf(v.x); o[1] = (short)f2bf(v.y);
    o[2] = (short)f2bf(v.z); o[3] = (short)f2bf(v.w);
  } else {
    o[0] = 0; o[1] = 0; o[2] = 0; o[3] = 0;
  }
  *(s16x4*)(dst + i) = o;
}

// ---------------------------------------------------------------------------
// GEMM v2.2 (small-N shapes): C[M,N] = A[M,K](bf16) @ B[N,K](bf16)^T
// BM=64, BK=64, BN template {64,128}. Double-buffered LDS, one-tile-ahead
// prefetch with COUNTED vmcnt. XOR-swizzled LDS on DMA source + fragment read.
// SPLITK>1: blockIdx.z computes K-slice, writes partial at z*M*Nc (MODE 0 only).
template <int BN, int MODE, int SPLITK>
__global__ __launch_bounds__(256)
void gemm2(const u16* __restrict__ A, const u16* __restrict__ B,
           float* __restrict__ C, u16* __restrict__ Cb,
           const u16* __restrict__ aux, int M, int Nc, int K) {
  constexpr int NJ = BN / 32;
  constexpr int BISS = BN / 32;
  constexpr int ABUF = 64 * 64;
  constexpr int BBUF = BN * 64;
  __shared__ __align__(16) u16 As[2 * ABUF];
  __shared__ __align__(16) u16 Bs[2 * BBUF];
  const int tid = threadIdx.x;
  const int tm0 = blockIdx.y * 64;
  const int tn0 = blockIdx.x * BN;
  const int kslice = K / SPLITK;
  const int k0 = blockIdx.z * kslice;
  const int wave = tid >> 6;
  const int lane = tid & 63;
  const int wm = (wave >> 1) * 32;
  const int wn = (wave & 1) * (BN / 2);
  const int frow = lane & 15;
  const int fc = lane >> 4;
  const int rmask = frow & 7;

  const int r0 = tid >> 3;
  const int csw = (((tid & 7) ^ (r0 & 7)) << 3);
  const u16* gA = A + (size_t)(tm0 + r0) * K + k0 + csw;
  const u16* gB = B + (size_t)(tn0 + r0) * K + k0 + csw;
  u16* lA = &As[tid * 8];
  u16* lB = &Bs[tid * 8];

  f32x4 acc[2][NJ];
  f32x4 zero = {0.f, 0.f, 0.f, 0.f};
#pragma unroll
  for (int i = 0; i < 2; ++i)
#pragma unroll
    for (int j = 0; j < NJ; ++j) acc[i][j] = zero;

  auto stage = [&](int bi) {
    gld_lds16(gA, lA + bi * ABUF);
    gld_lds16(gA + (size_t)32 * K, lA + bi * ABUF + 2048);
#pragma unroll
    for (int b = 0; b < BISS; ++b)
      gld_lds16(gB + (size_t)32 * b * K, lB + bi * BBUF + b * 2048);
    gA += 64; gB += 64;
  };

  stage(0);
  const int nt = kslice >> 6;
  int buf = 0;
  for (int kt = 0; kt < nt; ++kt) {
    const int nb = buf ^ 1;
    if (kt + 1 < nt) {
      stage(nb);
      if constexpr (BN == 64) asm volatile("s_waitcnt vmcnt(4)" ::: "memory");
      else                    asm volatile("s_waitcnt vmcnt(6)" ::: "memory");
    } else {
      asm volatile("s_waitcnt vmcnt(0)" ::: "memory");
    }
    __builtin_amdgcn_s_barrier();
    __builtin_amdgcn_sched_barrier(0);
    const int ao = buf * ABUF, bo = buf * BBUF;
#pragma unroll
    for (int s = 0; s < 2; ++s) {
      bf16x8 af[2], bfr[NJ];
#pragma unroll
      for (int i = 0; i < 2; ++i) {
        int addr = ao + (wm + i * 16 + frow) * 64 + (((s * 4 + fc) ^ rmask) << 3);
        af[i] = __builtin_bit_cast(bf16x8, *(const s16x8*)&As[addr]);
      }
#pragma unroll
      for (int j = 0; j < NJ; ++j) {
        int addr = bo + (wn + j * 16 + frow) * 64 + (((s * 4 + fc) ^ rmask) << 3);
        bfr[j] = __builtin_bit_cast(bf16x8, *(const s16x8*)&Bs[addr]);
      }
#pragma unroll
      for (int i = 0; i < 2; ++i)
#pragma unroll
        for (int j = 0; j < NJ; ++j)
          acc[i][j] = __builtin_amdgcn_mfma_f32_16x16x32_bf16(af[i], bfr[j], acc[i][j], 0, 0, 0);
    }
    __builtin_amdgcn_s_barrier();
    buf = nb;
  }
  const int ccol = lane & 15;
  const int crow = (lane >> 4) * 4;
  float* Cp = C + (size_t)blockIdx.z * ((size_t)M * Nc);
#pragma unroll
  for (int i = 0; i < 2; ++i) {
#pragma unroll
    for (int j = 0; j < NJ; ++j) {
      int gn = tn0 + wn + j * 16 + ccol;
      if (gn < Nc) {
        size_t base = (size_t)(tm0 + wm + i * 16 + crow) * Nc + gn;
#pragma unroll
        for (int r = 0; r < 4; ++r) {
          float c = acc[i][j][r];
          size_t idx = base + (size_t)r * Nc;
          if (MODE == 0) {
            Cp[idx] = c;
          } else if (MODE == 1) {
            Cb[idx] = f2bf(c * fast_sig(c));
          } else {
            Cb[idx] = f2bf(c * bf2f(aux[idx]));
          }
        }
      }
    }
  }
}

// ---------------------------------------------------------------------------
// GEMM v4.3: BM=128, BN=128, BK=64, 4 waves x 64x64 (4x4 frags), fused
// fp32->bf16 B conversion. Rotated schedule: ALL issue work hides under MFMA.
// Per K-step t (after B1): WRITEB(B(t+1) -> other buf, regs ~1 iter old so the
// compiler's wait is ~free); stageA(t+1) DMA; LOADB(B(t+2)) into the same reg
// set (WAR: loads issue after cvt reads); [compute(t)]; lgkmcnt(0); B2;
// vmcnt(8) retires exactly A(t+1) (B(t+2) newer, stays in flight); B1.
// Single brg reg set, static indexing throughout (rule #20). 2 barriers/step.
// SPLITK>1: blockIdx.z computes K-slice, writes partial C at z*M*Nc (MODE 0).
template <int MODE, int SPLITK>
__global__ __launch_bounds__(256)
void gemm128f(const u16* __restrict__ A, const float* __restrict__ Bw,
              float* __restrict__ C, u16* __restrict__ Cb,
              const u16* __restrict__ aux, int M, int Nc, int K) {
  __shared__ __align__(16) u16 As[2 * 8192];   // 32 KB
  __shared__ __align__(16) u16 Bs[2 * 8192];   // 32 KB
  const int tid = threadIdx.x;
  const int tm0 = blockIdx.y * 128;
  const int tn0 = blockIdx.x * 128;
  const int kslice = K / SPLITK;
  const int k0 = blockIdx.z * kslice;
  const int wave = tid >> 6;
  const int lane = tid & 63;
  const int wm = (wave >> 1) * 64;
  const int wn = (wave & 1) * 64;
  const int frow = lane & 15;
  const int fc = lane >> 4;
  const int rmask = frow & 7;

  const int r0 = tid >> 3;                        // LDS row (of 32-row group)
  const int csw = (((tid & 7) ^ (r0 & 7)) << 3);  // swizzled chunk offset
  // A: DMA with source-side swizzle, linear LDS dest
  const u16* gA = A + (size_t)(tm0 + r0) * K + k0 + csw;
  u16* lA = &As[tid * 8];
  // B: linear fp32 global source; swizzle applied on the ds_write address
  const float* gBf = Bw + (size_t)(tn0 + r0) * K + k0 + (tid & 7) * 8;
  u16* lBw = &Bs[r0 * 64 + csw];

  f32x4 acc[4][4];
  f32x4 zero = {0.f, 0.f, 0.f, 0.f};
#pragma unroll
  for (int i = 0; i < 4; ++i)
#pragma unroll
    for (int j = 0; j < 4; ++j) acc[i][j] = zero;

  float4 brg[4][2];   // single in-flight B tile register set

#define LOADB() do {                                    \
    _Pragma("unroll")                                   \
    for (int b = 0; b < 4; ++b) {                       \
      const float* p = gBf + (size_t)(32 * b) * K;      \
      brg[b][0] = *(const float4*)p;                    \
      brg[b][1] = *(const float4*)(p + 4);              \
    }                                                   \
    gBf += 64;                                          \
  } while (0)

#define WRITEB(BI) do {                                 \
    _Pragma("unroll")                                   \
    for (int b = 0; b < 4; ++b) {                       \
      uint4 o;                                          \
      o.x = cvtpk_bf16(brg[b][0].x, brg[b][0].y);       \
      o.y = cvtpk_bf16(brg[b][0].z, brg[b][0].w);       \
      o.z = cvtpk_bf16(brg[b][1].x, brg[b][1].y);       \
      o.w = cvtpk_bf16(brg[b][1].z, brg[b][1].w);       \
      *(uint4*)(lBw + (BI) * 8192 + b * 2048) = o;      \
    }                                                   \
  } while (0)

  auto stageA = [&](int bi) {
#pragma unroll
    for (int b = 0; b < 4; ++b)
      gld_lds16(gA + (size_t)(32 * b) * K, lA + bi * 8192 + b * 2048);
    gA += 64;
  };
  auto compute = [&](int boff) {
#pragma unroll
    for (int s = 0; s < 2; ++s) {
      bf16x8 af[4], bfr[4];
#pragma unroll
      for (int i = 0; i < 4; ++i) {
        int addr = boff + (wm + i * 16 + frow) * 64 + (((s * 4 + fc) ^ rmask) << 3);
        af[i] = __builtin_bit_cast(bf16x8, *(const s16x8*)&As[addr]);
      }
#pragma unroll
      for (int j = 0; j < 4; ++j) {
        int addr = boff + (wn + j * 16 + frow) * 64 + (((s * 4 + fc) ^ rmask) << 3);
        bfr[j] = __builtin_bit_cast(bf16x8, *(const s16x8*)&Bs[addr]);
      }
#pragma unroll
      for (int i = 0; i < 4; ++i)
#pragma unroll
        for (int j = 0; j < 4; ++j)
          acc[i][j] = __builtin_amdgcn_mfma_f32_16x16x32_bf16(af[i], bfr[j], acc[i][j], 0, 0, 0);
    }
  };

  const int nt = kslice >> 6;   // >= 16 for all shapes used here
  // prologue: B(0)->brg [8]; A(0) DMA [4, newest]; cvt+write B(0) into buf0
  // (compiler wait retires B(0), leaves A(0) in flight); B(1)->brg [8];
  // vmcnt(8) retires A(0) keeping B(1) in flight; barrier.
  LOADB();
  stageA(0);
  WRITEB(0);
  LOADB();
  asm volatile("s_waitcnt vmcnt(8) lgkmcnt(0)" ::: "memory");
  __builtin_amdgcn_s_barrier();               // B1 (tile 0 ready)
  __builtin_amdgcn_sched_barrier(0);

  int buf = 0;
  for (int kt = 0; kt < nt; ++kt) {
    const int nb = buf ^ 1;
    if (kt + 1 < nt) {
      // B(kt+1) regs ~1 iteration old -> compiler's wait before cvt is ~free.
      WRITEB(nb);
      stageA(nb);                             // A(kt+1) [4]
      if (kt + 2 < nt) LOADB();               // B(kt+2) [8, newest]
      __builtin_amdgcn_sched_barrier(0);      // pin issue cluster before MFMA
    }
    compute(buf * 8192);
    asm volatile("s_waitcnt lgkmcnt(0)" ::: "memory");  // ds_writes drained
    __builtin_amdgcn_s_barrier();             // B2: releases buf for reuse
    if (kt + 1 < nt) {
      if (kt + 2 < nt) asm volatile("s_waitcnt vmcnt(8)" ::: "memory");
      else             asm volatile("s_waitcnt vmcnt(0)" ::: "memory");
      __builtin_amdgcn_s_barrier();           // B1: A(kt+1)+B(kt+1) ready
      __builtin_amdgcn_sched_barrier(0);
    }
    buf = nb;
  }
#undef LOADB
#undef WRITEB

  const int ccol = lane & 15;
  const int crow = (lane >> 4) * 4;
  float* Cp = C + (size_t)blockIdx.z * ((size_t)M * Nc);
#pragma unroll
  for (int i = 0; i < 4; ++i) {
#pragma unroll
    for (int j = 0; j < 4; ++j) {
      int gn = tn0 + wn + j * 16 + ccol;
      size_t base = (size_t)(tm0 + wm + i * 16 + crow) * Nc + gn;
#pragma unroll
      for (int r = 0; r < 4; ++r) {
        float c = acc[i][j][r];
        size_t idx = base + (size_t)r * Nc;
        if (MODE == 0) {
          Cp[idx] = c;
        } else if (MODE == 1) {
          Cb[idx] = f2bf(c * fast_sig(c));
        } else {
          Cb[idx] = f2bf(c * bf2f(aux[idx]));
        }
      }
    }
  }
}

// ---------------------------------------------------------------------------
__device__ inline float block_reduce_sum_256(float v) {
  __shared__ float red[4];
  int lane = threadIdx.x & 63, wave = threadIdx.x >> 6;
#pragma unroll
  for (int m = 32; m > 0; m >>= 1) v += __shfl_xor(v, m, 64);
  if (lane == 0) red[wave] = v;
  __syncthreads();
  return red[0] + red[1] + red[2] + red[3];
}

// rmsnorm over C=2048 -> bf16 out
__global__ __launch_bounds__(256)
void rmsnorm2048_k(const float* __restrict__ x, const float* __restrict__ w,
                   u16* __restrict__ y) {
  const int C = 2048;
  const int row = blockIdx.x;
  const int t = threadIdx.x;
  const float4* xr = (const float4*)(x + (size_t)row * C);
  float4 v0 = xr[t];
  float4 v1 = xr[t + 256];
  float ss = v0.x * v0.x + v0.y * v0.y + v0.z * v0.z + v0.w * v0.w +
             v1.x * v1.x + v1.y * v1.y + v1.z * v1.z + v1.w * v1.w;
  float tot = block_reduce_sum_256(ss);
  float sc = rsqrtf(tot * (1.0f / C) + 1e-6f);
  const float4* wr = (const float4*)w;
  float4 w0 = wr[t], w1 = wr[t + 256];
  u16* yr = y + (size_t)row * C;
  s16x4 o0, o1;
  o0[0] = (short)f2bf(v0.x * sc * w0.x); o0[1] = (short)f2bf(v0.y * sc * w0.y);
  o0[2] = (short)f2bf(v0.z * sc * w0.z); o0[3] = (short)f2bf(v0.w * sc * w0.w);
  o1[0] = (short)f2bf(v1.x * sc * w1.x); o1[1] = (short)f2bf(v1.y * sc * w1.y);
  o1[2] = (short)f2bf(v1.z * sc * w1.z); o1[3] = (short)f2bf(v1.w * sc * w1.w);
  *(s16x4*)(yr + t * 4) = o0;
  *(s16x4*)(yr + 1024 + t * 4) = o1;
}

// residual = a + sum(4 split-K partials) (fp32), x2 = bf16(rmsnorm(residual)*w)
__global__ __launch_bounds__(256)
void add_rmsnorm4_k(const float* __restrict__ a, const float* __restrict__ p,
                    const float* __restrict__ w, float* __restrict__ resid,
                    u16* __restrict__ y) {
  const int C = 2048;
  const size_t S = (size_t)1024 * 2048;
  const int row = blockIdx.x;
  const int t = threadIdx.x;
  const float4* ar = (const float4*)(a + (size_t)row * C);
  float4 v0 = ar[t], v1 = ar[t + 256];
#pragma unroll
  for (int s = 0; s < 4; ++s) {
    const float4* br = (const float4*)(p + s * S + (size_t)row * C);
    float4 u0 = br[t], u1 = br[t + 256];
    v0.x += u0.x; v0.y += u0.y; v0.z += u0.z; v0.w += u0.w;
    v1.x += u1.x; v1.y += u1.y; v1.z += u1.z; v1.w += u1.w;
  }
  float4* rr = (float4*)(resid + (size_t)row * C);
  rr[t] = v0; rr[t + 256] = v1;
  float ss = v0.x * v0.x + v0.y * v0.y + v0.z * v0.z + v0.w * v0.w +
             v1.x * v1.x + v1.y * v1.y + v1.z * v1.z + v1.w * v1.w;
  float tot = block_reduce_sum_256(ss);
  float sc = rsqrtf(tot * (1.0f / C) + 1e-6f);
  const float4* wr = (const float4*)w;
  float4 w0 = wr[t], w1 = wr[t + 256];
  u16* yr = y + (size_t)row * C;
  s16x4 o0, o1;
  o0[0] = (short)f2bf(v0.x * sc * w0.x); o0[1] = (short)f2bf(v0.y * sc * w0.y);
  o0[2] = (short)f2bf(v0.z * sc * w0.z); o0[3] = (short)f2bf(v0.w * sc * w0.w);
  o1[0] = (short)f2bf(v1.x * sc * w1.x); o1[1] = (short)f2bf(v1.y * sc * w1.y);
  o1[2] = (short)f2bf(v1.z * sc * w1.z); o1[3] = (short)f2bf(v1.w * sc * w1.w);
  *(s16x4*)(yr + t * 4) = o0;
  *(s16x4*)(yr + 1024 + t * 4) = o1;
}

// causal depthwise conv (K=4) + bias + silu -> bf16 h
__global__ __launch_bounds__(256)
void conv_silu_k(const float* __restrict__ proj, const float* __restrict__ cw,
                 const float* __restrict__ cb, u16* __restrict__ h) {
  const int Di = 4096, LD = 8192;
  int idx = blockIdx.x * 256 + threadIdx.x;
  int d = idx & (Di - 1);
  int l = idx >> 12;
  float4 w = *(const float4*)(cw + (size_t)d * 4);
  float acc = cb[d];
  int ls0 = l - 3;
  if (ls0 >= 0) acc += proj[(size_t)ls0 * LD + d] * w.x;
  if (ls0 + 1 >= 0) acc += proj[(size_t)(ls0 + 1) * LD + d] * w.y;
  if (ls0 + 2 >= 0) acc += proj[(size_t)(ls0 + 2) * LD + d] * w.z;
  acc += proj[(size_t)l * LD + d] * w.w;
  h[idx] = f2bf(acc * fast_sig(acc));
}

// three rmsnorms over the 160-wide ssm rows (summing 4 split-K partials):
// dt[128]->bf16, B[16], C[16]
__global__ __launch_bounds__(64)
void ssm_norm_k(const float* __restrict__ ssmp, const float* __restrict__ dtw,
                const float* __restrict__ bw, const float* __restrict__ cw,
                u16* __restrict__ dtn, float* __restrict__ Bn,
                float* __restrict__ Cn) {
  const size_t S = (size_t)1024 * 160;
  int l = blockIdx.x;
  int lane = threadIdx.x;
  float d0 = 0.f, d1 = 0.f, bv = 0.f, cv = 0.f;
#pragma unroll
  for (int s = 0; s < 4; ++s) {
    const float* r = ssmp + s * S + (size_t)l * 160;
    d0 += r[lane];
    d1 += r[lane + 64];
    if (lane < 16) {
      bv += r[128 + lane];
      cv += r[144 + lane];
    }
  }
  float sd = d0 * d0 + d1 * d1;
  float sb = bv * bv;
  float sc = cv * cv;
#pragma unroll
  for (int m = 32; m > 0; m >>= 1) {
    sd += __shfl_xor(sd, m, 64);
    sb += __shfl_xor(sb, m, 64);
    sc += __shfl_xor(sc, m, 64);
  }
  float scd = rsqrtf(sd * (1.f / 128.f) + 1e-6f);
  float scb = rsqrtf(sb * (1.f / 16.f) + 1e-6f);
  float scc = rsqrtf(sc * (1.f / 16.f) + 1e-6f);
  dtn[(size_t)l * 128 + lane] = f2bf(d0 * scd * dtw[lane]);
  dtn[(size_t)l * 128 + lane + 64] = f2bf(d1 * scd * dtw[lane + 64]);
  if (lane < 16) {
    Bn[(size_t)l * 16 + lane] = bv * scb * bw[lane];
    Cn[(size_t)l * 16 + lane] = cv * scc * cw[lane];
  }
}

// ---------------------------------------------------------------------------
// Chunked parallel scan over L=1024: NCH chunks of CHL.
#define NCH 32
#define CHL 32

__global__ __launch_bounds__(256)
void scan_p1(const float* __restrict__ dpre, const float* __restrict__ dtb,
             const u16* __restrict__ h, const float* __restrict__ Bn,
             const float* __restrict__ Amat,
             float* __restrict__ carryA, float* __restrict__ carryS) {
  const int Di = 4096;
  int chunk = blockIdx.x & (NCH - 1);
  int d = (blockIdx.x >> 5) * 256 + threadIdx.x;
  __shared__ float Bs[CHL * 16];
  for (int i = threadIdx.x; i < CHL * 16; i += 256)
    Bs[i] = Bn[(size_t)chunk * CHL * 16 + i];
  __syncthreads();
  float a[16];
#pragma unroll
  for (int q = 0; q < 4; ++q)
    *(float4*)&a[q * 4] = *(const float4*)(Amat + (size_t)d * 16 + q * 4);
  float bias = dtb[d];
  float s[16];
#pragma unroll
  for (int n = 0; n < 16; ++n) s[n] = 0.f;
  float sumdel = 0.f;
  int l0 = chunk * CHL;
#pragma unroll 4
  for (int j = 0; j < CHL; ++j) {
    int l = l0 + j;
    float del = fast_softplus(dpre[(size_t)l * Di + d] + bias);
    float hv = bf2f(h[(size_t)l * Di + d]);
    sumdel += del;
    float c = del * hv;
#pragma unroll
    for (int n = 0; n < 16; ++n) {
      float dA = __expf(del * a[n]);
      s[n] = dA * s[n] + c * Bs[j * 16 + n];
    }
  }
  size_t base = (size_t)chunk * 65536 + (size_t)d * 16;
#pragma unroll
  for (int n = 0; n < 16; ++n) {
    carryA[base + n] = __expf(sumdel * a[n]);
    carryS[base + n] = s[n];
  }
}

__global__ __launch_bounds__(256)
void scan_p2(const float* __restrict__ carryA, float* __restrict__ carryS) {
  int p = blockIdx.x * 256 + threadIdx.x;
  float cin = 0.f;
#pragma unroll
  for (int c = 0; c < NCH; ++c) {
    float av = carryA[(size_t)c * 65536 + p];
    float sv = carryS[(size_t)c * 65536 + p];
    float nx = av * cin + sv;
    carryS[(size_t)c * 65536 + p] = cin;
    cin = nx;
  }
}

__global__ __launch_bounds__(256)
void scan_p3(const float* __restrict__ dpre, const float* __restrict__ dtb,
             const u16* __restrict__ h, const float* __restrict__ Bn,
             const float* __restrict__ Cn, const float* __restrict__ Amat,
             const float* __restrict__ Dw, const float* __restrict__ proj,
             const float* __restrict__ carryS, u16* __restrict__ y) {
  const int Di = 4096;
  int chunk = blockIdx.x & (NCH - 1);
  int d = (blockIdx.x >> 5) * 256 + threadIdx.x;
  __shared__ float Bs[CHL * 16];
  __shared__ float Cs[CHL * 16];
  for (int i = threadIdx.x; i < CHL * 16; i += 256) {
    Bs[i] = Bn[(size_t)chunk * CHL * 16 + i];
    Cs[i] = Cn[(size_t)chunk * CHL * 16 + i];
  }
  __syncthreads();
  float a[16];
#pragma unroll
  for (int q = 0; q < 4; ++q)
    *(float4*)&a[q * 4] = *(const float4*)(Amat + (size_t)d * 16 + q * 4);
  float bias = dtb[d];
  float Dd = Dw[d];
  float s[16];
  size_t base = (size_t)chunk * 65536 + (size_t)d * 16;
#pragma unroll
  for (int q = 0; q < 4; ++q)
    *(float4*)&s[q * 4] = *(const float4*)(carryS + base + q * 4);
  int l0 = chunk * CHL;
#pragma unroll 2
  for (int j = 0; j < CHL; ++j) {
    int l = l0 + j;
    float del = fast_softplus(dpre[(size_t)l * Di + d] + bias);
    float hv = bf2f(h[(size_t)l * Di + d]);
    float c = del * hv;
    float p = 0.f;
#pragma unroll
    for (int n = 0; n < 16; ++n) {
      float dA = __expf(del * a[n]);
      s[n] = dA * s[n] + c * Bs[j * 16 + n];
      p += s[n] * Cs[j * 16 + n];
    }
    float g = proj[(size_t)l * 8192 + 4096 + d];
    float yv = p + hv * Dd;
    y[(size_t)l * Di + d] = f2bf(yv * g * fast_sig(g));
  }
}

// out += p0+p1+p2+p3 (split-K partials)
__global__ __launch_bounds__(256)
void add4_k(float* __restrict__ out, const float* __restrict__ p) {
  const size_t S = (size_t)1024 * 2048;
  int i = blockIdx.x * 256 + threadIdx.x;
  float4 a = ((const float4*)out)[i];
#pragma unroll
  for (int s = 0; s < 4; ++s) {
    float4 b = ((const float4*)(p + s * S))[i];
    a.x += b.x; a.y += b.y; a.z += b.z; a.w += b.w;
  }
  ((float4*)out)[i] = a;
}

// ---------------------------------------------------------------------------
extern "C" void kernel_launch(void* const* d_in, const int* in_sizes, int n_in,
                              void* d_out, int out_size, void* d_ws, size_t ws_size,
                              hipStream_t stream) {
  const float* hidden      = (const float*)d_in[0];
  const float* in_ln_w     = (const float*)d_in[1];
  const float* pre_ff_ln_w = (const float*)d_in[2];
  const float* in_proj_w   = (const float*)d_in[3];
  const float* conv_w      = (const float*)d_in[4];
  const float* conv_b      = (const float*)d_in[5];
  const float* x_proj_w    = (const float*)d_in[6];
  const float* dt_ln_w     = (const float*)d_in[7];
  const float* b_ln_w      = (const float*)d_in[8];
  const float* c_ln_w      = (const float*)d_in[9];
  const float* dt_proj_w   = (const float*)d_in[10];
  const float* dt_proj_b   = (const float*)d_in[11];
  const float* Amat        = (const float*)d_in[12];
  const float* Dw          = (const float*)d_in[13];
  const float* out_proj_w  = (const float*)d_in[14];
  const float* gate_up_w   = (const float*)d_in[15];
  const float* down_w      = (const float*)d_in[16];
  float* out = (float*)d_out;
  float* ws = (float*)d_ws;

  const int L = 1024, H = 2048, Di = 4096, F = 8192;

  // workspace (float-element offsets), peak ~106 MB
  u16*   wbuf   = (u16*)ws;                  // small-weight slab (bf16)
  float* carryA = ws + 2097152;              // NCH x 65536
  float* carryS = ws + 4194304;              // NCH x 65536
  float* proj   = ws + 8388608;              // L x 8192 fp32
  float* dpre   = ws + 16777216;             // L x 4096 fp32 (raw dt GEMM out)
  float* ssmp   = ws + 16777216;             // 4 x (L x 160) split-K partials
                                             // (in dpre hole; dead before dpre)
  u16*   hbuf   = (u16*)(ws + 20971520);     // L x 4096 bf16
  u16*   xnorm  = (u16*)(ws + 23068672);     // L x 2048 bf16
  u16*   dtn    = (u16*)(ws + 24281088);     // L x 128 bf16
  float* Bn     = ws + 24346624;             // L x 16
  float* Cn     = ws + 24363008;             // L x 16
  u16*   ybuf   = (u16*)(ws + 24379392);     // L x 4096 bf16
  float* mixp   = ws + 8388608;              // 4 x (L x 2048) split-K partials
  u16*   x2     = (u16*)(ws + 18874368);     // L x 2048 bf16
  u16*   sg     = (u16*)(ws + 8388608);      // L x 8192 bf16 (reuse proj)
  u16*   x3     = (u16*)(ws + 12582912);     // L x 8192 bf16 (reuse proj)
  float* ffp    = ws + 16777216;             // 4 x (L x 2048) split-K partials

  // 1. x_norm = bf16(rmsnorm(hidden))
  rmsnorm2048_k<<<L, 256, 0, stream>>>(hidden, in_ln_w, xnorm);
  // 2. proj = x_norm @ in_proj_w.T  (N=8192, K=2048)  [fused fp32-B, rotated]
  gemm128f<0, 1><<<dim3(64, 8), 256, 0, stream>>>(xnorm, in_proj_w, proj, nullptr, nullptr, L, 8192, 2048);
  // 3. h = bf16(silu(conv(proj[:, :Di]) + conv_b))
  conv_silu_k<<<(L * Di) / 256, 256, 0, stream>>>(proj, conv_w, conv_b, hbuf);
  // 4. ssm = h @ x_proj_w.T  (N=160 padded to 256, K=4096, split-K=4)
  f32_to_bf16_k<<<1024, 256, 0, stream>>>(x_proj_w, wbuf, 1048576, 655360);
  gemm2<64, 0, 4><<<dim3(4, 16, 4), 256, 0, stream>>>(hbuf, wbuf, ssmp, nullptr, nullptr, L, 160, 4096);
  // 5. split rmsnorms (sums the 4 ssm partials)
  ssm_norm_k<<<L, 64, 0, stream>>>(ssmp, dt_ln_w, b_ln_w, c_ln_w, dtn, Bn, Cn);
  // 6. delta_pre = dtn @ dt_proj_w.T  (N=4096, K=128)
  f32_to_bf16_k<<<512, 256, 0, stream>>>(dt_proj_w, wbuf, 524288, 524288);
  gemm2<128, 0, 1><<<dim3(32, 16), 256, 0, stream>>>(dtn, wbuf, dpre, nullptr, nullptr, L, 4096, 128);
  // 7-8. chunked scan (softplus fused, n-in-registers) -> ybuf (bf16)
  scan_p1<<<16 * NCH, 256, 0, stream>>>(dpre, dt_proj_b, hbuf, Bn, Amat, carryA, carryS);
  scan_p2<<<256, 256, 0, stream>>>(carryA, carryS);
  scan_p3<<<16 * NCH, 256, 0, stream>>>(dpre, dt_proj_b, hbuf, Bn, Cn, Amat, Dw, proj, carryS, ybuf);
  // 9. mix = y @ out_proj_w.T  (N=2048, K=4096)  [split-K=4 -> 512 blocks]
  gemm128f<0, 4><<<dim3(16, 8, 4), 256, 0, stream>>>(ybuf, out_proj_w, mixp, nullptr, nullptr, L, 2048, 4096);
  // 10. residual(out) = hidden + sum(mixp) ; x2 = bf16(rmsnorm(residual))
  add_rmsnorm4_k<<<L, 256, 0, stream>>>(hidden, mixp, pre_ff_ln_w, out, x2);
  // 11a. sg = bf16(silu(x2 @ gate_w.T))  (N=8192, K=2048)
  gemm128f<1, 1><<<dim3(64, 8), 256, 0, stream>>>(x2, gate_up_w, nullptr, sg, nullptr, L, 8192, 2048);
  // 11b. x3 = bf16((x2 @ up_w.T) * sg)
  gemm128f<2, 1><<<dim3(64, 8), 256, 0, stream>>>(x2, gate_up_w + 16777216, nullptr, x3, sg, L, 8192, 2048);
  // 13. ff = x3 @ down_w.T  (N=2048, K=8192)  [split-K=4 -> 512 blocks]
  gemm128f<0, 4><<<dim3(16, 8, 4), 256, 0, stream>>>(x3, down_w, ffp, nullptr, nullptr, L, 2048, 8192);
  // 14. out += sum(ffp)
  add4_k<<<(L * H / 4) / 256, 256, 0, stream>>>(out, ffp);
}